// Round 17
// baseline (863.853 us; speedup 1.0000x reference)
//
#include <hip/hip_runtime.h>
#include <hip/hip_bf16.h>
#include <stdint.h>

#define BB 64
#define TT 32
#define HID 512
#define XD  512
#define NV  10000

#define GRID   512
#define NCELL  128
#define VB     32
#define NLOG   313       // ceil(10000/32)
#define LOGB   128       // logits blocks 128..440
#define NORMB  441       // reduce blocks 441..504 (one per batch row)
#define TOKSENT 0xFFFFFFFFu

typedef __bf16 bf16x8 __attribute__((ext_vector_type(8)));
typedef float  f32x4  __attribute__((ext_vector_type(4)));
typedef unsigned u32x4 __attribute__((ext_vector_type(4)));

__device__ inline void split2(float w, __bf16& hi, __bf16& lo) {
  hi = (__bf16)w;
  lo = (__bf16)(w - (float)hi);
}

__device__ inline unsigned long long shflxor64(unsigned long long v, int m) {
  unsigned lo = (unsigned)(v & 0xFFFFFFFFull);
  unsigned hi = (unsigned)(v >> 32);
  lo = __shfl_xor(lo, m);
  hi = __shfl_xor(hi, m);
  return ((unsigned long long)hi << 32) | lo;
}

// monotonic packing of (logit, vocab index); larger u64 = larger logit,
// ties broken toward SMALLER index (matches jnp.argmax first-occurrence).
__device__ inline unsigned long long packkey(float f, int v) {
  unsigned ub = __float_as_uint(f);
  unsigned key = (ub & 0x80000000u) ? ~ub : (ub | 0x80000000u);
  return ((unsigned long long)key << 32) | (unsigned)(0xFFFFFFFFu - (unsigned)v);
}

// device-coherent (write-through to LLC) 16B store
__device__ inline void st_wt16(void* addr, u32x4 d) {
  asm volatile("global_store_dwordx4 %0, %1, off sc0 sc1"
               :: "v"(addr), "v"(d) : "memory");
}

// ---- sync: 16-way line-spread relaxed counters, WAVE-PARALLEL poll ----
__device__ inline void spinP(int* base, int target) {
  if (threadIdx.x < 64) {
    int lane = threadIdx.x;
    int s;
    do {
      int v = 0;
      if (lane < 16)
        v = __hip_atomic_load(base + lane * 16, __ATOMIC_RELAXED,
                              __HIP_MEMORY_SCOPE_AGENT);
      #pragma unroll
      for (int m = 1; m < 16; m <<= 1) v += __shfl_xor(v, m);
      s = __shfl(v, 0);
      if (s < target) __builtin_amdgcn_s_sleep(1);
    } while (s < target);
  }
  __syncthreads();
}
// drain write-through stores (vmcnt 0), barrier, one relaxed bump
__device__ inline void publish(int* base) {
  asm volatile("s_waitcnt vmcnt(0)" ::: "memory");
  __syncthreads();
  if (threadIdx.x == 0)
    __hip_atomic_fetch_add(base + (blockIdx.x & 15) * 16, 1,
                           __ATOMIC_RELAXED, __HIP_MEMORY_SCOPE_AGENT);
}
// sentinel poll on a u32 slot (value doubles as the ready flag)
__device__ inline unsigned poll_u32(unsigned* addr) {
  unsigned v;
  do {
    v = __hip_atomic_load(addr, __ATOMIC_RELAXED, __HIP_MEMORY_SCOPE_AGENT);
    if (v == TOKSENT) __builtin_amdgcn_s_sleep(1);
  } while (v == TOKSENT);
  return v;
}

struct Params {
  const float *x, *emb;
  const float *Whi, *Whf, *Who, *Whz;
  const float *Wxi, *Wxf, *Wxo, *Wxz;
  const float *bi, *bfg, *bo, *bz;
  const float *W_lin, *b_lin;
  float* out;
  char* hb;                    // [TT+1][128][64][16B]  (group, hi4|lo4)
  char* xb;                    // [TT][128][64][16B]    pre-split emb rows
  float* c_ws;
  float* psum;                 // [TT][NLOG][64] f32 (t-unique)
  unsigned long long* pmax;    // [TT][NLOG][64] u64
  unsigned* tok;               // [TT][BB]  sentinel-init; doubles as xb-ready
  unsigned* inv;               // [TT][BB]  f32 bits; sentinel-init
  int* ctr;                    // [2][TT][16][16]  (cd, ld)
};

// rebuild hi/lo bf16x8 for (tt,row,k-frag kk) from two 16B loads
__device__ inline void loadH(const char* hb, int tt, int row, int kk,
                             bf16x8& ah, bf16x8& al) {
  size_t off = (((size_t)tt * 128 + (kk >> 2)) * 64 + row) * 16;
  uint4 v0 = *(const uint4*)(hb + off);
  uint4 v1 = *(const uint4*)(hb + off + 1024);   // next group
  union { unsigned u[4]; bf16x8 v; } A, B;
  A.u[0] = v0.x; A.u[1] = v0.y; A.u[2] = v1.x; A.u[3] = v1.y;
  B.u[0] = v0.z; B.u[1] = v0.w; B.u[2] = v1.z; B.u[3] = v1.w;
  ah = A.v; al = B.v;
}

struct SMCell { __bf16 Ch[16][1042]; __bf16 Cl[16][1042]; float pre[64][17]; };
struct SMLog  { __bf16 Bh[32][522];  __bf16 Bl[32][522]; };
union SMU { SMCell c; SMLog l; };

__global__ __launch_bounds__(256) void k_init(
    const float* __restrict__ h0, const float* __restrict__ c0,
    char* __restrict__ hb, float* __restrict__ c_ws,
    int* __restrict__ ctrs, unsigned* __restrict__ tok,
    unsigned* __restrict__ inv) {
  int i = blockIdx.x * 256 + threadIdx.x;   // 128 blocks = BB*HID threads
  int row = i >> 9, k = i & 511, g = k >> 2, q = k & 3;
  float h = h0[i];
  __bf16 hi, lo; split2(h, hi, lo);
  char* base = hb + (((size_t)g) * 64 + row) * 16;   // t=0
  ((unsigned short*)base)[q]       = __builtin_bit_cast(unsigned short, hi);
  ((unsigned short*)(base + 8))[q] = __builtin_bit_cast(unsigned short, lo);
  c_ws[i] = c0[i];
  if (i < 2 * TT * 256) ctrs[i] = 0;
  if (i < TT * BB) { tok[i] = TOKSENT; inv[i] = TOKSENT; }
}

__global__ __launch_bounds__(256, 2) void k_main(Params p) {
  __shared__ SMU sm;
  __shared__ float red_s[4];
  __shared__ unsigned long long red_m[4];
  __shared__ unsigned sh_tok;
  const int bid = blockIdx.x, tid = threadIdx.x;
  const int lane = tid & 63, wid = tid >> 6;

  int* cd0 = p.ctr;                    // [TT][256]
  int* ld0 = p.ctr + TT * 256;

  // ======================= CELL blocks 0..127 =======================
  if (bid < NCELL) {
    const int n0 = bid * 4;
    const float* WH[4] = {p.Whi, p.Whf, p.Who, p.Whz};
    const float* WX[4] = {p.Wxi, p.Wxf, p.Wxo, p.Wxz};

    // one-time stage: 16 rows (gate g, col j) x K=1024 (h:0..511, x:512..1023)
    #pragma unroll
    for (int i2 = 0; i2 < 16; i2++) {
      int e = tid + i2 * 256;          // e = k*4 + g
      int k = e >> 2, g = e & 3;
      const float* src = (k < HID) ? (WH[g] + (size_t)k * HID + n0)
                                   : (WX[g] + (size_t)(k - HID) * HID + n0);
      float4 w = *(const float4*)src;
      #pragma unroll
      for (int j = 0; j < 4; j++) {
        __bf16 hi, lo; split2(((const float*)&w)[j], hi, lo);
        sm.c.Ch[g * 4 + j][k] = hi;
        sm.c.Cl[g * 4 + j][k] = lo;
      }
    }
    __syncthreads();

    const int row  = wid * 16 + (lane & 15);
    const int brow = lane & 15;

    for (int t = 0; t < TT; t++) {
      if (t > 0) spinP(cd0 + (t - 1) * 256, NCELL);   // h[t] fully published

      f32x4 accA = {0.f, 0.f, 0.f, 0.f};
      f32x4 accB = {0.f, 0.f, 0.f, 0.f};

      // h-part FIRST (needs only cd[t-1]) — overlaps logits/reduce of t-1
      #pragma unroll
      for (int ks = 0; ks < 16; ks++) {
        int kk = ks * 32 + (lane >> 4) * 8;
        bf16x8 ah, al;
        loadH(p.hb, t, row, kk, ah, al);
        bf16x8 bh = *(const bf16x8*)&sm.c.Ch[brow][kk];
        bf16x8 bl = *(const bf16x8*)&sm.c.Cl[brow][kk];
        accA = __builtin_amdgcn_mfma_f32_16x16x32_bf16(ah, bh, accA, 0, 0, 0);
        accB = __builtin_amdgcn_mfma_f32_16x16x32_bf16(ah, bl, accB, 0, 0, 0);
        accB = __builtin_amdgcn_mfma_f32_16x16x32_bf16(al, bh, accB, 0, 0, 0);
        accA = __builtin_amdgcn_mfma_f32_16x16x32_bf16(al, bl, accA, 0, 0, 0);
      }

      // x-part: t==0 from input x; else pre-split xb[t-1] gated by PER-ROW
      // tok sentinel (tok[t-1][row] != SENT implies row's xb+inv visible)
      if (t == 0) {
        const float* xrow = p.x + (size_t)row * TT * XD;
        #pragma unroll
        for (int ks = 16; ks < 32; ks++) {
          int kk = ks * 32 + (lane >> 4) * 8;        // 512..1016
          const float* xp = xrow + (kk - HID);
          float4 w0 = *(const float4*)(xp);
          float4 w1 = *(const float4*)(xp + 4);
          bf16x8 ah, al;
          #pragma unroll
          for (int j = 0; j < 4; j++) {
            __bf16 hi, lo;
            split2(((const float*)&w0)[j], hi, lo); ah[j] = hi; al[j] = lo;
            split2(((const float*)&w1)[j], hi, lo); ah[4 + j] = hi; al[4 + j] = lo;
          }
          bf16x8 bh = *(const bf16x8*)&sm.c.Ch[brow][kk];
          bf16x8 bl = *(const bf16x8*)&sm.c.Cl[brow][kk];
          accA = __builtin_amdgcn_mfma_f32_16x16x32_bf16(ah, bh, accA, 0, 0, 0);
          accB = __builtin_amdgcn_mfma_f32_16x16x32_bf16(ah, bl, accB, 0, 0, 0);
          accB = __builtin_amdgcn_mfma_f32_16x16x32_bf16(al, bh, accB, 0, 0, 0);
          accA = __builtin_amdgcn_mfma_f32_16x16x32_bf16(al, bl, accA, 0, 0, 0);
        }
      } else {
        (void)poll_u32(&p.tok[(size_t)(t - 1) * BB + row]);   // row-granular
        #pragma unroll
        for (int ks = 16; ks < 32; ks++) {
          int kk = ks * 32 + (lane >> 4) * 8;
          bf16x8 ah, al;
          loadH(p.xb, t - 1, row, kk - 512, ah, al);
          bf16x8 bh = *(const bf16x8*)&sm.c.Ch[brow][kk];
          bf16x8 bl = *(const bf16x8*)&sm.c.Cl[brow][kk];
          accA = __builtin_amdgcn_mfma_f32_16x16x32_bf16(ah, bh, accA, 0, 0, 0);
          accB = __builtin_amdgcn_mfma_f32_16x16x32_bf16(ah, bl, accB, 0, 0, 0);
          accB = __builtin_amdgcn_mfma_f32_16x16x32_bf16(al, bh, accB, 0, 0, 0);
          accA = __builtin_amdgcn_mfma_f32_16x16x32_bf16(al, bl, accA, 0, 0, 0);
        }
      }

      #pragma unroll
      for (int j = 0; j < 4; j++)
        sm.c.pre[wid * 16 + (lane >> 4) * 4 + j][lane & 15] = accA[j] + accB[j];
      __syncthreads();

      float cnv; int rl, nn;
      {
        int rloc = tid >> 2, q = tid & 3;
        int n = n0 + q;
        float pi = sm.c.pre[rloc][q]      + p.bi[n];
        float pf = sm.c.pre[rloc][4 + q]  + p.bfg[n];
        float pq = sm.c.pre[rloc][8 + q]  + p.bo[n];
        float pz = sm.c.pre[rloc][12 + q] + p.bz[n];
        float ig = 1.f / (1.f + expf(-pi));
        float fg = 1.f / (1.f + expf(-pf));
        float og = 1.f / (1.f + expf(-pq));
        float zg = tanhf(pz);
        float cp = p.c_ws[rloc * HID + n];
        float cn = ig * zg + fg * cp;
        float hn = og * tanhf(cn);
        __bf16 hh, hl; split2(hn, hh, hl);
        unsigned hhu = (unsigned)__builtin_bit_cast(unsigned short, hh);
        unsigned hlu = (unsigned)__builtin_bit_cast(unsigned short, hl);
        unsigned hi1 = __shfl_down(hhu, 1), hi2 = __shfl_down(hhu, 2),
                 hi3 = __shfl_down(hhu, 3);
        unsigned lo1 = __shfl_down(hlu, 1), lo2 = __shfl_down(hlu, 2),
                 lo3 = __shfl_down(hlu, 3);
        if (q == 0) {
          u32x4 d = { hhu | (hi1 << 16), hi2 | (hi3 << 16),
                      hlu | (lo1 << 16), lo2 | (lo3 << 16) };
          st_wt16(p.hb + (((size_t)(t + 1) * 128 + bid) * 64 + rloc) * 16, d);
        }
        cnv = cn; rl = rloc; nn = n;
      }
      publish(cd0 + t * 256);          // drains only the h wt-stores
      // c-state stores AFTER publish: HBM store latency off the chain
      p.c_ws[rl * HID + nn] = cnv;
      p.out[(size_t)BB * TT * NV + (size_t)rl * TT * HID + (size_t)t * HID + nn] = cnv;
    }
    return;
  }

  // ======================= LOGITS blocks 128..440 =======================
  if (bid < NORMB) {
    const int lb = bid - LOGB;
    const int v0 = lb * VB;
    const int row = wid * 16 + (lane & 15);

    float bcar[2];
    float evp[2][4];   // previous step's exp values (y written one step late)

    auto stageW = [&](int widx) {
      const float* W = p.W_lin + (size_t)widx * HID * NV;
      float4 v[16];
      #pragma unroll
      for (int i2 = 0; i2 < 16; i2++) {
        int e = tid + i2 * 256;          // e = k*8 + pp
        int k = e >> 3, pp = e & 7;
        v[i2] = *(const float4*)(W + (size_t)k * NV + v0 + pp * 4);
      }
      const float* bn = p.b_lin + (size_t)widx * NV;
      bcar[0] = bn[v0 + (lane & 15)];
      bcar[1] = bn[v0 + 16 + (lane & 15)];   // may over-read; masked later
      #pragma unroll
      for (int i2 = 0; i2 < 16; i2++) {
        int e = tid + i2 * 256;
        int k = e >> 3, pp = e & 7;
        #pragma unroll
        for (int j = 0; j < 4; j++) {
          __bf16 hi, lo; split2(((const float*)&v[i2])[j], hi, lo);
          sm.l.Bh[pp * 4 + j][k] = hi;
          sm.l.Bl[pp * 4 + j][k] = lo;
        }
      }
    };

    stageW(0);   // logits(0) uses lidx=0

    for (int t = 0; t < TT; t++) {
      spinP(cd0 + t * 256, NCELL);     // h[t+1] published; barrier covers LDS

      f32x4 acc[2][2] = {};
      #pragma unroll
      for (int ks = 0; ks < 16; ks++) {
        int kk = ks * 32 + (lane >> 4) * 8;
        bf16x8 ah, al;
        loadH(p.hb, t + 1, row, kk, ah, al);
        #pragma unroll
        for (int vt = 0; vt < 2; vt++) {
          int rrow = vt * 16 + (lane & 15);
          bf16x8 bh = *(const bf16x8*)&sm.l.Bh[rrow][kk];
          bf16x8 bl = *(const bf16x8*)&sm.l.Bl[rrow][kk];
          acc[vt][0] = __builtin_amdgcn_mfma_f32_16x16x32_bf16(ah, bh, acc[vt][0], 0, 0, 0);
          acc[vt][1] = __builtin_amdgcn_mfma_f32_16x16x32_bf16(ah, bl, acc[vt][1], 0, 0, 0);
          acc[vt][1] = __builtin_amdgcn_mfma_f32_16x16x32_bf16(al, bh, acc[vt][1], 0, 0, 0);
          acc[vt][0] = __builtin_amdgcn_mfma_f32_16x16x32_bf16(al, bl, acc[vt][0], 0, 0, 0);
        }
      }

      float ev[2][4];
      float rsum[4] = {0.f, 0.f, 0.f, 0.f};
      unsigned long long rmax[4] = {0ULL, 0ULL, 0ULL, 0ULL};
      #pragma unroll
      for (int vt = 0; vt < 2; vt++) {
        int v = v0 + vt * 16 + (lane & 15);
        bool ok = (v < NV);
        float bb = ok ? bcar[vt] : 0.f;
        #pragma unroll
        for (int j = 0; j < 4; j++) {
          float logit = acc[vt][0][j] + acc[vt][1][j] + bb;
          float e = ok ? expf(logit) : 0.f;   // no max-subtract: |logit| small
          ev[vt][j] = e;
          rsum[j] += e;
          if (ok) {
            unsigned long long pk = packkey(logit, v);
            if (pk > rmax[j]) rmax[j] = pk;
          }
        }
      }

      #pragma unroll
      for (int off = 1; off < 16; off <<= 1) {
        #pragma unroll
        for (int j = 0; j < 4; j++) {
          rsum[j] += __shfl_xor(rsum[j], off);
          unsigned long long o = shflxor64(rmax[j], off);
          if (o > rmax[j]) rmax[j] = o;
        }
      }
      if ((lane & 15) == 0) {
        int rbase = wid * 16 + (lane >> 4) * 4;
        union { float f[4]; u32x4 u; } S;
        S.f[0] = rsum[0]; S.f[1] = rsum[1]; S.f[2] = rsum[2]; S.f[3] = rsum[3];
        st_wt16(&p.psum[((size_t)t * NLOG + lb) * 64 + rbase], S.u);
        u32x4 M0 = { (unsigned)rmax[0], (unsigned)(rmax[0] >> 32),
                     (unsigned)rmax[1], (unsigned)(rmax[1] >> 32) };
        u32x4 M1 = { (unsigned)rmax[2], (unsigned)(rmax[2] >> 32),
                     (unsigned)rmax[3], (unsigned)(rmax[3] >> 32) };
        st_wt16(&p.pmax[((size_t)t * NLOG + lb) * 64 + rbase], M0);
        st_wt16(&p.pmax[((size_t)t * NLOG + lb) * 64 + rbase + 2], M1);
      }
      publish(ld0 + t * 256);           // tiny drain: 3 wide stores

      if (t < TT - 1) stageW(t);        // overlaps reduce(t) + cell(t+1)

      // write y(t-1): cd[t] implies tok[t-1] seen by all cells, which
      // implies inv[t-1] visible (reducer stores inv before tok) — plain read
      if (t > 0) {
        float invr[4];
        #pragma unroll
        for (int j = 0; j < 4; j++)
          invr[j] = __builtin_bit_cast(float,
              p.inv[(size_t)(t - 1) * BB + wid * 16 + (lane >> 4) * 4 + j]);
        #pragma unroll
        for (int vt = 0; vt < 2; vt++) {
          int v = v0 + vt * 16 + (lane & 15);
          if (v < NV) {
            #pragma unroll
            for (int j = 0; j < 4; j++) {
              int r = wid * 16 + (lane >> 4) * 4 + j;
              p.out[(size_t)r * TT * NV + (size_t)(t - 1) * NV + v] = evp[vt][j] * invr[j];
            }
          }
        }
      }
      #pragma unroll
      for (int vt = 0; vt < 2; vt++)
        #pragma unroll
        for (int j = 0; j < 4; j++) evp[vt][j] = ev[vt][j];
    }

    // final y(31): poll inv sentinel directly (per-row)
    float invr[4];
    #pragma unroll
    for (int j = 0; j < 4; j++) {
      unsigned iv = poll_u32(&p.inv[(size_t)(TT - 1) * BB +
                                    wid * 16 + (lane >> 4) * 4 + j]);
      invr[j] = __builtin_bit_cast(float, iv);
    }
    #pragma unroll
    for (int vt = 0; vt < 2; vt++) {
      int v = v0 + vt * 16 + (lane & 15);
      if (v < NV) {
        #pragma unroll
        for (int j = 0; j < 4; j++) {
          int r = wid * 16 + (lane >> 4) * 4 + j;
          p.out[(size_t)r * TT * NV + (size_t)(TT - 1) * NV + v] = evp[vt][j] * invr[j];
        }
      }
    }
    return;
  }

  // ================= REDUCE blocks 441..504 (one per row) =============
  if (bid < NORMB + BB) {
    const int r = bid - NORMB;
    for (int t = 0; t < TT; t++) {
      spinP(ld0 + t * 256, NLOG);

      float s = 0.f; unsigned long long m = 0ULL;
      for (int i = tid; i < NLOG; i += 256) {
        s += p.psum[((size_t)t * NLOG + i) * 64 + r];
        unsigned long long v = p.pmax[((size_t)t * NLOG + i) * 64 + r];
        if (v > m) m = v;
      }
      #pragma unroll
      for (int off = 1; off < 64; off <<= 1) {
        s += __shfl_xor(s, off);
        unsigned long long o = shflxor64(m, off);
        if (o > m) m = o;
      }
      if (lane == 0) { red_s[wid] = s; red_m[wid] = m; }
      __syncthreads();
      if (tid == 0) {
        s = red_s[0] + red_s[1] + red_s[2] + red_s[3];
        m = red_m[0];
        if (red_m[1] > m) m = red_m[1];
        if (red_m[2] > m) m = red_m[2];
        if (red_m[3] > m) m = red_m[3];
        sh_tok = 0xFFFFFFFFu - (unsigned)(m & 0xFFFFFFFFull);
        // inv stored BEFORE the tok flag (visibility rides tok's drain)
        float iv = 1.0f / s;
        __hip_atomic_store(&p.inv[(size_t)t * BB + r],
                           __builtin_bit_cast(unsigned, iv),
                           __ATOMIC_RELAXED, __HIP_MEMORY_SCOPE_AGENT);
      }
      __syncthreads();

      // pre-split next-step x row: emb[tok] -> xb[t] (hi4|lo4 16B groups)
      unsigned tokv = sh_tok;
      if (tid < 128) {
        float4 w = *(const float4*)(p.emb + (size_t)tokv * XD + tid * 4);
        unsigned h[4], l[4];
        #pragma unroll
        for (int j = 0; j < 4; j++) {
          __bf16 hi, lo; split2(((const float*)&w)[j], hi, lo);
          h[j] = (unsigned)__builtin_bit_cast(unsigned short, hi);
          l[j] = (unsigned)__builtin_bit_cast(unsigned short, lo);
        }
        u32x4 d = { h[0] | (h[1] << 16), h[2] | (h[3] << 16),
                    l[0] | (l[1] << 16), l[2] | (l[3] << 16) };
        st_wt16(p.xb + (((size_t)t * 128 + tid) * 64 + r) * 16, d);
      }
      // drain inv + xb stores, then set the per-row tok flag (the signal)
      asm volatile("s_waitcnt vmcnt(0)" ::: "memory");
      __syncthreads();
      if (tid == 0)
        __hip_atomic_store(&p.tok[(size_t)t * BB + r], tokv,
                           __ATOMIC_RELAXED, __HIP_MEMORY_SCOPE_AGENT);
      __syncthreads();          // red_s/red_m/sh_tok reuse safety
    }
    return;
  }
  // blocks 505..511 idle
}

extern "C" void kernel_launch(void* const* d_in, const int* in_sizes, int n_in,
                              void* d_out, int out_size, void* d_ws, size_t ws_size,
                              hipStream_t stream) {
  const float* x     = (const float*)d_in[0];
  const float* h0    = (const float*)d_in[1];
  const float* c0    = (const float*)d_in[2];
  const float* W_hi  = (const float*)d_in[3];
  const float* W_xi  = (const float*)d_in[4];
  const float* b_i   = (const float*)d_in[5];
  const float* W_hf  = (const float*)d_in[6];
  const float* W_xf  = (const float*)d_in[7];
  const float* b_f   = (const float*)d_in[8];
  const float* W_ho  = (const float*)d_in[9];
  const float* W_xo  = (const float*)d_in[10];
  const float* b_o   = (const float*)d_in[11];
  const float* W_hz  = (const float*)d_in[12];
  const float* W_xz  = (const float*)d_in[13];
  const float* b_z   = (const float*)d_in[14];
  const float* W_lin = (const float*)d_in[15];
  const float* b_lin = (const float*)d_in[16];
  const float* emb   = (const float*)d_in[17];

  float* out = (float*)d_out;
  char* ws = (char*)d_ws;
  // layout (bytes):
  char*   hb   = ws;                                              // 33*128*64*16 = 4,325,376
  char*   xb   = ws + 4325376;                                    // 32*128*64*16 = 4,194,304
  float*  c_ws = (float*)(ws + 8519680);                          //      131,072
  float*  psum = (float*)(ws + 8650752);                          // 32*313*64*4 = 2,564,096
  unsigned long long* pmax = (unsigned long long*)(ws + 11214848);// 32*313*64*8 = 5,128,192
  unsigned* tok = (unsigned*)(ws + 16343040);                     //        8,192
  unsigned* inv = (unsigned*)(ws + 16351232);                     //        8,192
  int*    ctrs = (int*)(ws + 16359424);                           // 2*32*256*4 = 65,536

  k_init<<<128, 256, 0, stream>>>(h0, c0, hb, c_ws, ctrs, tok, inv);

  Params P;
  P.x = x; P.emb = emb;
  P.Whi = W_hi; P.Whf = W_hf; P.Who = W_ho; P.Whz = W_hz;
  P.Wxi = W_xi; P.Wxf = W_xf; P.Wxo = W_xo; P.Wxz = W_xz;
  P.bi = b_i; P.bfg = b_f; P.bo = b_o; P.bz = b_z;
  P.W_lin = W_lin; P.b_lin = b_lin;
  P.out = out;
  P.hb = hb; P.xb = xb; P.c_ws = c_ws;
  P.psum = psum; P.pmax = pmax;
  P.tok = tok; P.inv = inv;
  P.ctr = ctrs;

  k_main<<<GRID, 256, 0, stream>>>(P);
}

// Round 18
// 746.830 us; speedup vs baseline: 1.1567x; 1.1567x over previous
//
#include <hip/hip_runtime.h>
#include <hip/hip_bf16.h>
#include <stdint.h>

#define BB 64
#define TT 32
#define HID 512
#define XD  512
#define NV  10000

#define GRID   512
#define NCELL  128
#define VB     32
#define NLOG   313       // ceil(10000/32)
#define LOGB   128       // logits blocks 128..440
#define NORMB  441       // reduce blocks 441..504 (one per batch row)

typedef __bf16 bf16x8 __attribute__((ext_vector_type(8)));
typedef float  f32x4  __attribute__((ext_vector_type(4)));
typedef unsigned u32x4 __attribute__((ext_vector_type(4)));

__device__ inline void split2(float w, __bf16& hi, __bf16& lo) {
  hi = (__bf16)w;
  lo = (__bf16)(w - (float)hi);
}

__device__ inline unsigned long long shflxor64(unsigned long long v, int m) {
  unsigned lo = (unsigned)(v & 0xFFFFFFFFull);
  unsigned hi = (unsigned)(v >> 32);
  lo = __shfl_xor(lo, m);
  hi = __shfl_xor(hi, m);
  return ((unsigned long long)hi << 32) | lo;
}

// monotonic packing of (logit, vocab index); larger u64 = larger logit,
// ties broken toward SMALLER index (matches jnp.argmax first-occurrence).
__device__ inline unsigned long long packkey(float f, int v) {
  unsigned ub = __float_as_uint(f);
  unsigned key = (ub & 0x80000000u) ? ~ub : (ub | 0x80000000u);
  return ((unsigned long long)key << 32) | (unsigned)(0xFFFFFFFFu - (unsigned)v);
}

// device-coherent (write-through to LLC) 16B store
__device__ inline void st_wt16(void* addr, u32x4 d) {
  asm volatile("global_store_dwordx4 %0, %1, off sc0 sc1"
               :: "v"(addr), "v"(d) : "memory");
}

// ---- sync: NL-line-spread relaxed counters, WAVE-PARALLEL poll ----
// Each counter has NL sub-counters, one per 64B line. Lane i polls line i
// (one wave memory instr per round), butterfly-sum over 64 lanes.
template<int NL>
__device__ inline void spinN(int* base, int target) {
  if (threadIdx.x < 64) {
    int lane = threadIdx.x;
    int s;
    do {
      int v = 0;
      if (NL >= 64 || lane < NL)
        v = __hip_atomic_load(base + lane * 16, __ATOMIC_RELAXED,
                              __HIP_MEMORY_SCOPE_AGENT);
      #pragma unroll
      for (int m = 1; m < 64; m <<= 1) v += __shfl_xor(v, m);
      s = v;
      if (s < target) __builtin_amdgcn_s_sleep(1);
    } while (s < target);
  }
  __syncthreads();
}
// drain write-through stores (vmcnt 0), barrier, one relaxed bump
template<int NL>
__device__ inline void publishN(int* base) {
  asm volatile("s_waitcnt vmcnt(0)" ::: "memory");
  __syncthreads();
  if (threadIdx.x == 0)
    __hip_atomic_fetch_add(base + (blockIdx.x & (NL - 1)) * 16, 1,
                           __ATOMIC_RELAXED, __HIP_MEMORY_SCOPE_AGENT);
}

struct Params {
  const float *x, *emb, *c0;
  const float *Whi, *Whf, *Who, *Whz;
  const float *Wxi, *Wxf, *Wxo, *Wxz;
  const float *bi, *bfg, *bo, *bz;
  const float *W_lin, *b_lin;
  float* out;
  char* hb;                    // [TT+1][128][64][16B]  (group, hi4|lo4)
  char* xb;                    // [TT][128][64][16B]    pre-split emb rows
  float* psum;                 // [TT][NLOG][64] f32 (t-unique)
  unsigned long long* pmax;    // [TT][NLOG][64] u64
  float* inv;                  // [TT][BB]
  int* ctr;                    // cd [TT][32][16] | ld [TT][64][16] | rn [TT][16][16]
};

// rebuild hi/lo bf16x8 for (tt,row,k-frag kk) from two 16B loads
__device__ inline void loadH(const char* hb, int tt, int row, int kk,
                             bf16x8& ah, bf16x8& al) {
  size_t off = (((size_t)tt * 128 + (kk >> 2)) * 64 + row) * 16;
  uint4 v0 = *(const uint4*)(hb + off);
  uint4 v1 = *(const uint4*)(hb + off + 1024);   // next group
  union { unsigned u[4]; bf16x8 v; } A, B;
  A.u[0] = v0.x; A.u[1] = v0.y; A.u[2] = v1.x; A.u[3] = v1.y;
  B.u[0] = v0.z; B.u[1] = v0.w; B.u[2] = v1.z; B.u[3] = v1.w;
  ah = A.v; al = B.v;
}

struct SMCell { __bf16 Ch[16][1042]; __bf16 Cl[16][1042]; float pre[64][17]; };
struct SMLog  { __bf16 Bh[32][522];  __bf16 Bl[32][522]; };
union SMU { SMCell c; SMLog l; };

#define CTR_TOTAL (TT * 512 + TT * 1024 + TT * 256)   // 57,344 ints

__global__ __launch_bounds__(256) void k_init(
    const float* __restrict__ h0,
    char* __restrict__ hb, int* __restrict__ ctrs) {
  int i = blockIdx.x * 256 + threadIdx.x;   // 128 blocks = BB*HID threads
  int row = i >> 9, k = i & 511, g = k >> 2, q = k & 3;
  float h = h0[i];
  __bf16 hi, lo; split2(h, hi, lo);
  char* base = hb + (((size_t)g) * 64 + row) * 16;   // t=0
  ((unsigned short*)base)[q]       = __builtin_bit_cast(unsigned short, hi);
  ((unsigned short*)(base + 8))[q] = __builtin_bit_cast(unsigned short, lo);
  for (int j = i; j < CTR_TOTAL; j += 128 * 256) ctrs[j] = 0;
}

__global__ __launch_bounds__(256, 2) void k_main(Params p) {
  __shared__ SMU sm;
  __shared__ float red_s[4];
  __shared__ unsigned long long red_m[4];
  __shared__ unsigned sh_tok;
  const int bid = blockIdx.x, tid = threadIdx.x;
  const int lane = tid & 63, wid = tid >> 6;

  int* cd0 = p.ctr;                        // [TT][32][16]
  int* ld0 = p.ctr + TT * 512;             // [TT][64][16]
  int* rn0 = p.ctr + TT * 512 + TT * 1024; // [TT][16][16]

  // ======================= CELL blocks 0..127 =======================
  if (bid < NCELL) {
    const int n0 = bid * 4;
    const float* WH[4] = {p.Whi, p.Whf, p.Who, p.Whz};
    const float* WX[4] = {p.Wxi, p.Wxf, p.Wxo, p.Wxz};

    // one-time stage: 16 rows (gate g, col j) x K=1024 (h:0..511, x:512..1023)
    #pragma unroll
    for (int i2 = 0; i2 < 16; i2++) {
      int e = tid + i2 * 256;          // e = k*4 + g
      int k = e >> 2, g = e & 3;
      const float* src = (k < HID) ? (WH[g] + (size_t)k * HID + n0)
                                   : (WX[g] + (size_t)(k - HID) * HID + n0);
      float4 w = *(const float4*)src;
      #pragma unroll
      for (int j = 0; j < 4; j++) {
        __bf16 hi, lo; split2(((const float*)&w)[j], hi, lo);
        sm.c.Ch[g * 4 + j][k] = hi;
        sm.c.Cl[g * 4 + j][k] = lo;
      }
    }
    __syncthreads();

    const int row  = wid * 16 + (lane & 15);
    const int brow = lane & 15;
    const int rl0  = tid >> 2, nn0 = n0 + (tid & 3);
    float creg = p.c0[rl0 * HID + nn0];   // persistent cell state in register

    for (int t = 0; t < TT; t++) {
      if (t > 0) spinN<32>(cd0 + (t - 1) * 512, NCELL);   // h[t] published

      f32x4 accA = {0.f, 0.f, 0.f, 0.f};
      f32x4 accB = {0.f, 0.f, 0.f, 0.f};

      // h-part FIRST (needs only cd[t-1]) — overlaps logits/reduce of t-1
      #pragma unroll
      for (int ks = 0; ks < 16; ks++) {
        int kk = ks * 32 + (lane >> 4) * 8;
        bf16x8 ah, al;
        loadH(p.hb, t, row, kk, ah, al);
        bf16x8 bh = *(const bf16x8*)&sm.c.Ch[brow][kk];
        bf16x8 bl = *(const bf16x8*)&sm.c.Cl[brow][kk];
        accA = __builtin_amdgcn_mfma_f32_16x16x32_bf16(ah, bh, accA, 0, 0, 0);
        accB = __builtin_amdgcn_mfma_f32_16x16x32_bf16(ah, bl, accB, 0, 0, 0);
        accB = __builtin_amdgcn_mfma_f32_16x16x32_bf16(al, bh, accB, 0, 0, 0);
        accA = __builtin_amdgcn_mfma_f32_16x16x32_bf16(al, bl, accA, 0, 0, 0);
      }

      // x-part: t==0 from input x; else pre-split xb[t-1] (written by reducers)
      if (t == 0) {
        const float* xrow = p.x + (size_t)row * TT * XD;
        #pragma unroll
        for (int ks = 16; ks < 32; ks++) {
          int kk = ks * 32 + (lane >> 4) * 8;        // 512..1016
          const float* xp = xrow + (kk - HID);
          float4 w0 = *(const float4*)(xp);
          float4 w1 = *(const float4*)(xp + 4);
          bf16x8 ah, al;
          #pragma unroll
          for (int j = 0; j < 4; j++) {
            __bf16 hi, lo;
            split2(((const float*)&w0)[j], hi, lo); ah[j] = hi; al[j] = lo;
            split2(((const float*)&w1)[j], hi, lo); ah[4 + j] = hi; al[4 + j] = lo;
          }
          bf16x8 bh = *(const bf16x8*)&sm.c.Ch[brow][kk];
          bf16x8 bl = *(const bf16x8*)&sm.c.Cl[brow][kk];
          accA = __builtin_amdgcn_mfma_f32_16x16x32_bf16(ah, bh, accA, 0, 0, 0);
          accB = __builtin_amdgcn_mfma_f32_16x16x32_bf16(ah, bl, accB, 0, 0, 0);
          accB = __builtin_amdgcn_mfma_f32_16x16x32_bf16(al, bh, accB, 0, 0, 0);
          accA = __builtin_amdgcn_mfma_f32_16x16x32_bf16(al, bl, accA, 0, 0, 0);
        }
      } else {
        spinN<16>(rn0 + (t - 1) * 256, BB);          // xb[t-1] published
        #pragma unroll
        for (int ks = 16; ks < 32; ks++) {
          int kk = ks * 32 + (lane >> 4) * 8;
          bf16x8 ah, al;
          loadH(p.xb, t - 1, row, kk - 512, ah, al);
          bf16x8 bh = *(const bf16x8*)&sm.c.Ch[brow][kk];
          bf16x8 bl = *(const bf16x8*)&sm.c.Cl[brow][kk];
          accA = __builtin_amdgcn_mfma_f32_16x16x32_bf16(ah, bh, accA, 0, 0, 0);
          accB = __builtin_amdgcn_mfma_f32_16x16x32_bf16(ah, bl, accB, 0, 0, 0);
          accB = __builtin_amdgcn_mfma_f32_16x16x32_bf16(al, bh, accB, 0, 0, 0);
          accA = __builtin_amdgcn_mfma_f32_16x16x32_bf16(al, bl, accA, 0, 0, 0);
        }
      }

      #pragma unroll
      for (int j = 0; j < 4; j++)
        sm.c.pre[wid * 16 + (lane >> 4) * 4 + j][lane & 15] = accA[j] + accB[j];
      __syncthreads();

      float cnv;
      {
        float pi = sm.c.pre[rl0][(tid & 3)]      + p.bi[nn0];
        float pf = sm.c.pre[rl0][4 + (tid & 3)]  + p.bfg[nn0];
        float pq = sm.c.pre[rl0][8 + (tid & 3)]  + p.bo[nn0];
        float pz = sm.c.pre[rl0][12 + (tid & 3)] + p.bz[nn0];
        float ig = 1.f / (1.f + expf(-pi));
        float fg = 1.f / (1.f + expf(-pf));
        float og = 1.f / (1.f + expf(-pq));
        float zg = tanhf(pz);
        float cn = ig * zg + fg * creg;
        creg = cn;
        float hn = og * tanhf(cn);
        __bf16 hh, hl; split2(hn, hh, hl);
        unsigned hhu = (unsigned)__builtin_bit_cast(unsigned short, hh);
        unsigned hlu = (unsigned)__builtin_bit_cast(unsigned short, hl);
        unsigned hi1 = __shfl_down(hhu, 1), hi2 = __shfl_down(hhu, 2),
                 hi3 = __shfl_down(hhu, 3);
        unsigned lo1 = __shfl_down(hlu, 1), lo2 = __shfl_down(hlu, 2),
                 lo3 = __shfl_down(hlu, 3);
        if ((tid & 3) == 0) {
          u32x4 d = { hhu | (hi1 << 16), hi2 | (hi3 << 16),
                      hlu | (lo1 << 16), lo2 | (lo3 << 16) };
          st_wt16(p.hb + (((size_t)(t + 1) * 128 + bid) * 64 + rl0) * 16, d);
        }
        cnv = cn;
      }
      publishN<32>(cd0 + t * 512);     // drains only the h wt-stores
      // c-state store AFTER publish: HBM store latency off the chain
      p.out[(size_t)BB * TT * NV + (size_t)rl0 * TT * HID + (size_t)t * HID + nn0] = cnv;
    }
    return;
  }

  // ======================= LOGITS blocks 128..440 =======================
  if (bid < NORMB) {
    const int lb = bid - LOGB;
    const int v0 = lb * VB;
    const int row = wid * 16 + (lane & 15);

    float bcar[2];
    float evp[2][4];   // previous step's exp values (y written one step late)

    auto stageW = [&](int widx) {
      const float* W = p.W_lin + (size_t)widx * HID * NV;
      float4 v[16];
      #pragma unroll
      for (int i2 = 0; i2 < 16; i2++) {
        int e = tid + i2 * 256;          // e = k*8 + pp
        int k = e >> 3, pp = e & 7;
        v[i2] = *(const float4*)(W + (size_t)k * NV + v0 + pp * 4);
      }
      const float* bn = p.b_lin + (size_t)widx * NV;
      bcar[0] = bn[v0 + (lane & 15)];
      bcar[1] = bn[v0 + 16 + (lane & 15)];   // may over-read; masked later
      #pragma unroll
      for (int i2 = 0; i2 < 16; i2++) {
        int e = tid + i2 * 256;
        int k = e >> 3, pp = e & 7;
        #pragma unroll
        for (int j = 0; j < 4; j++) {
          __bf16 hi, lo; split2(((const float*)&v[i2])[j], hi, lo);
          sm.l.Bh[pp * 4 + j][k] = hi;
          sm.l.Bl[pp * 4 + j][k] = lo;
        }
      }
    };

    stageW(0);   // logits(0) uses lidx=0

    for (int t = 0; t < TT; t++) {
      spinN<32>(cd0 + t * 512, NCELL); // h[t+1] published; barrier covers LDS

      f32x4 acc[2][2] = {};
      #pragma unroll
      for (int ks = 0; ks < 16; ks++) {
        int kk = ks * 32 + (lane >> 4) * 8;
        bf16x8 ah, al;
        loadH(p.hb, t + 1, row, kk, ah, al);
        #pragma unroll
        for (int vt = 0; vt < 2; vt++) {
          int rrow = vt * 16 + (lane & 15);
          bf16x8 bh = *(const bf16x8*)&sm.l.Bh[rrow][kk];
          bf16x8 bl = *(const bf16x8*)&sm.l.Bl[rrow][kk];
          acc[vt][0] = __builtin_amdgcn_mfma_f32_16x16x32_bf16(ah, bh, acc[vt][0], 0, 0, 0);
          acc[vt][1] = __builtin_amdgcn_mfma_f32_16x16x32_bf16(ah, bl, acc[vt][1], 0, 0, 0);
          acc[vt][1] = __builtin_amdgcn_mfma_f32_16x16x32_bf16(al, bh, acc[vt][1], 0, 0, 0);
          acc[vt][0] = __builtin_amdgcn_mfma_f32_16x16x32_bf16(al, bl, acc[vt][0], 0, 0, 0);
        }
      }

      float ev[2][4];
      float rsum[4] = {0.f, 0.f, 0.f, 0.f};
      unsigned long long rmax[4] = {0ULL, 0ULL, 0ULL, 0ULL};
      #pragma unroll
      for (int vt = 0; vt < 2; vt++) {
        int v = v0 + vt * 16 + (lane & 15);
        bool ok = (v < NV);
        float bb = ok ? bcar[vt] : 0.f;
        #pragma unroll
        for (int j = 0; j < 4; j++) {
          float logit = acc[vt][0][j] + acc[vt][1][j] + bb;
          float e = ok ? expf(logit) : 0.f;   // no max-subtract: |logit| small
          ev[vt][j] = e;
          rsum[j] += e;
          if (ok) {
            unsigned long long pk = packkey(logit, v);
            if (pk > rmax[j]) rmax[j] = pk;
          }
        }
      }

      #pragma unroll
      for (int off = 1; off < 16; off <<= 1) {
        #pragma unroll
        for (int j = 0; j < 4; j++) {
          rsum[j] += __shfl_xor(rsum[j], off);
          unsigned long long o = shflxor64(rmax[j], off);
          if (o > rmax[j]) rmax[j] = o;
        }
      }
      if ((lane & 15) == 0) {
        int rbase = wid * 16 + (lane >> 4) * 4;
        union { float f[4]; u32x4 u; } S;
        S.f[0] = rsum[0]; S.f[1] = rsum[1]; S.f[2] = rsum[2]; S.f[3] = rsum[3];
        st_wt16(&p.psum[((size_t)t * NLOG + lb) * 64 + rbase], S.u);
        u32x4 M0 = { (unsigned)rmax[0], (unsigned)(rmax[0] >> 32),
                     (unsigned)rmax[1], (unsigned)(rmax[1] >> 32) };
        u32x4 M1 = { (unsigned)rmax[2], (unsigned)(rmax[2] >> 32),
                     (unsigned)rmax[3], (unsigned)(rmax[3] >> 32) };
        st_wt16(&p.pmax[((size_t)t * NLOG + lb) * 64 + rbase], M0);
        st_wt16(&p.pmax[((size_t)t * NLOG + lb) * 64 + rbase + 2], M1);
      }
      publishN<64>(ld0 + t * 1024);     // tiny drain: 3 wide stores

      if (t < TT - 1) stageW(t);        // overlaps reduce(t) + cell(t+1)

      // write y(t-1): cd[t] implies rn[t-1], so inv[t-1] is valid (plain read)
      if (t > 0) {
        float invr[4];
        #pragma unroll
        for (int j = 0; j < 4; j++)
          invr[j] = p.inv[(size_t)(t - 1) * BB + wid * 16 + (lane >> 4) * 4 + j];
        #pragma unroll
        for (int vt = 0; vt < 2; vt++) {
          int v = v0 + vt * 16 + (lane & 15);
          if (v < NV) {
            #pragma unroll
            for (int j = 0; j < 4; j++) {
              int r = wid * 16 + (lane >> 4) * 4 + j;
              p.out[(size_t)r * TT * NV + (size_t)(t - 1) * NV + v] = evp[vt][j] * invr[j];
            }
          }
        }
      }
      #pragma unroll
      for (int vt = 0; vt < 2; vt++)
        #pragma unroll
        for (int j = 0; j < 4; j++) evp[vt][j] = ev[vt][j];
    }

    // final y(31)
    spinN<16>(rn0 + (TT - 1) * 256, BB);
    float invr[4];
    #pragma unroll
    for (int j = 0; j < 4; j++)
      invr[j] = p.inv[(size_t)(TT - 1) * BB + wid * 16 + (lane >> 4) * 4 + j];
    #pragma unroll
    for (int vt = 0; vt < 2; vt++) {
      int v = v0 + vt * 16 + (lane & 15);
      if (v < NV) {
        #pragma unroll
        for (int j = 0; j < 4; j++) {
          int r = wid * 16 + (lane >> 4) * 4 + j;
          p.out[(size_t)r * TT * NV + (size_t)(TT - 1) * NV + v] = evp[vt][j] * invr[j];
        }
      }
    }
    return;
  }

  // ================= REDUCE blocks 441..504 (one per row) =============
  if (bid < NORMB + BB) {
    const int r = bid - NORMB;
    for (int t = 0; t < TT; t++) {
      spinN<64>(ld0 + t * 1024, NLOG);

      float s = 0.f; unsigned long long m = 0ULL;
      for (int i = tid; i < NLOG; i += 256) {
        s += p.psum[((size_t)t * NLOG + i) * 64 + r];
        unsigned long long v = p.pmax[((size_t)t * NLOG + i) * 64 + r];
        if (v > m) m = v;
      }
      #pragma unroll
      for (int off = 1; off < 64; off <<= 1) {
        s += __shfl_xor(s, off);
        unsigned long long o = shflxor64(m, off);
        if (o > m) m = o;
      }
      if (lane == 0) { red_s[wid] = s; red_m[wid] = m; }
      __syncthreads();
      if (tid == 0) {
        s = red_s[0] + red_s[1] + red_s[2] + red_s[3];
        m = red_m[0];
        if (red_m[1] > m) m = red_m[1];
        if (red_m[2] > m) m = red_m[2];
        if (red_m[3] > m) m = red_m[3];
        sh_tok = 0xFFFFFFFFu - (unsigned)(m & 0xFFFFFFFFull);
        __hip_atomic_store((unsigned*)&p.inv[(size_t)t * BB + r],
                           __builtin_bit_cast(unsigned, 1.0f / s),
                           __ATOMIC_RELAXED, __HIP_MEMORY_SCOPE_AGENT);
      }
      __syncthreads();

      // pre-split next-step x row: emb[tok] -> xb[t] (hi4|lo4 16B groups)
      unsigned tokv = sh_tok;
      if (tid < 128) {
        float4 w = *(const float4*)(p.emb + (size_t)tokv * XD + tid * 4);
        unsigned h[4], l[4];
        #pragma unroll
        for (int j = 0; j < 4; j++) {
          __bf16 hi, lo; split2(((const float*)&w)[j], hi, lo);
          h[j] = (unsigned)__builtin_bit_cast(unsigned short, hi);
          l[j] = (unsigned)__builtin_bit_cast(unsigned short, lo);
        }
        u32x4 d = { h[0] | (h[1] << 16), h[2] | (h[3] << 16),
                    l[0] | (l[1] << 16), l[2] | (l[3] << 16) };
        st_wt16(p.xb + (((size_t)t * 128 + tid) * 64 + r) * 16, d);
      }
      publishN<16>(rn0 + t * 256);   // drain inv + xb stores, then bump
      __syncthreads();               // red_s/red_m/sh_tok reuse safety
    }
    return;
  }
  // blocks 505..511 idle
}

extern "C" void kernel_launch(void* const* d_in, const int* in_sizes, int n_in,
                              void* d_out, int out_size, void* d_ws, size_t ws_size,
                              hipStream_t stream) {
  const float* x     = (const float*)d_in[0];
  const float* h0    = (const float*)d_in[1];
  const float* c0    = (const float*)d_in[2];
  const float* W_hi  = (const float*)d_in[3];
  const float* W_xi  = (const float*)d_in[4];
  const float* b_i   = (const float*)d_in[5];
  const float* W_hf  = (const float*)d_in[6];
  const float* W_xf  = (const float*)d_in[7];
  const float* b_f   = (const float*)d_in[8];
  const float* W_ho  = (const float*)d_in[9];
  const float* W_xo  = (const float*)d_in[10];
  const float* b_o   = (const float*)d_in[11];
  const float* W_hz  = (const float*)d_in[12];
  const float* W_xz  = (const float*)d_in[13];
  const float* b_z   = (const float*)d_in[14];
  const float* W_lin = (const float*)d_in[15];
  const float* b_lin = (const float*)d_in[16];
  const float* emb   = (const float*)d_in[17];

  float* out = (float*)d_out;
  char* ws = (char*)d_ws;
  // layout (bytes):
  char*   hb   = ws;                                              // 33*128*64*16 = 4,325,376
  char*   xb   = ws + 4325376;                                    // 32*128*64*16 = 4,194,304
  float*  psum = (float*)(ws + 8519680);                          // 32*313*64*4 = 2,564,096
  unsigned long long* pmax = (unsigned long long*)(ws + 11083776);// 32*313*64*8 = 5,128,192
  float*  inv  = (float*)(ws + 16211968);                         //        8,192
  int*    ctrs = (int*)(ws + 16220160);                           //      229,376

  k_init<<<128, 256, 0, stream>>>(h0, hb, ctrs);

  Params P;
  P.x = x; P.emb = emb; P.c0 = c0;
  P.Whi = W_hi; P.Whf = W_hf; P.Who = W_ho; P.Whz = W_hz;
  P.Wxi = W_xi; P.Wxf = W_xf; P.Wxo = W_xo; P.Wxz = W_xz;
  P.bi = b_i; P.bfg = b_f; P.bo = b_o; P.bz = b_z;
  P.W_lin = W_lin; P.b_lin = b_lin;
  P.out = out;
  P.hb = hb; P.xb = xb;
  P.psum = psum; P.pmax = pmax; P.inv = inv;
  P.ctr = ctrs;

  k_main<<<GRID, 256, 0, stream>>>(P);
}

// Round 19
// 714.382 us; speedup vs baseline: 1.2092x; 1.0454x over previous
//
#include <hip/hip_runtime.h>
#include <hip/hip_bf16.h>
#include <stdint.h>

#define BB 64
#define TT 32
#define HID 512
#define XD  512
#define NV  10000

#define GRID   512
#define NCELL  128
#define VB     32
#define NLOG   313       // ceil(10000/32)
#define LOGB   128       // logits blocks 128..440
#define NORMB  441       // reduce blocks 441..504 (one per batch row)

typedef __bf16 bf16x8 __attribute__((ext_vector_type(8)));
typedef float  f32x4  __attribute__((ext_vector_type(4)));
typedef unsigned u32x4 __attribute__((ext_vector_type(4)));

__device__ inline void split2(float w, __bf16& hi, __bf16& lo) {
  hi = (__bf16)w;
  lo = (__bf16)(w - (float)hi);
}

__device__ inline unsigned long long shflxor64(unsigned long long v, int m) {
  unsigned lo = (unsigned)(v & 0xFFFFFFFFull);
  unsigned hi = (unsigned)(v >> 32);
  lo = __shfl_xor(lo, m);
  hi = __shfl_xor(hi, m);
  return ((unsigned long long)hi << 32) | lo;
}

// monotonic packing of (logit, vocab index); larger u64 = larger logit,
// ties broken toward SMALLER index (matches jnp.argmax first-occurrence).
__device__ inline unsigned long long packkey(float f, int v) {
  unsigned ub = __float_as_uint(f);
  unsigned key = (ub & 0x80000000u) ? ~ub : (ub | 0x80000000u);
  return ((unsigned long long)key << 32) | (unsigned)(0xFFFFFFFFu - (unsigned)v);
}

// device-coherent (write-through to LLC) 16B store
__device__ inline void st_wt16(void* addr, u32x4 d) {
  asm volatile("global_store_dwordx4 %0, %1, off sc0 sc1"
               :: "v"(addr), "v"(d) : "memory");
}

// ---- sync: NL-line-spread relaxed counters, WAVE-PARALLEL poll ----
// Each counter has NL sub-counters, one per 64B line. Lane i polls lines
// i, i+64, ... (NL/64 wave memory instrs per round), butterfly-sum.
template<int NL>
__device__ inline void spinN(int* base, int target) {
  if (threadIdx.x < 64) {
    int lane = threadIdx.x;
    int s;
    do {
      int v = 0;
      #pragma unroll
      for (int i = 0; i < (NL + 63) / 64; i++) {
        int idx = lane + i * 64;
        if (NL % 64 == 0 || idx < NL)
          v += __hip_atomic_load(base + idx * 16, __ATOMIC_RELAXED,
                                 __HIP_MEMORY_SCOPE_AGENT);
      }
      #pragma unroll
      for (int m = 1; m < 64; m <<= 1) v += __shfl_xor(v, m);
      s = v;
      if (s < target) __builtin_amdgcn_s_sleep(1);
    } while (s < target);
  }
  __syncthreads();
}
// drain write-through stores (vmcnt 0), barrier, one relaxed bump
template<int NL>
__device__ inline void publishN(int* base) {
  asm volatile("s_waitcnt vmcnt(0)" ::: "memory");
  __syncthreads();
  if (threadIdx.x == 0)
    __hip_atomic_fetch_add(base + (blockIdx.x & (NL - 1)) * 16, 1,
                           __ATOMIC_RELAXED, __HIP_MEMORY_SCOPE_AGENT);
}

struct Params {
  const float *x, *emb, *c0;
  const float *Whi, *Whf, *Who, *Whz;
  const float *Wxi, *Wxf, *Wxo, *Wxz;
  const float *bi, *bfg, *bo, *bz;
  const float *W_lin, *b_lin;
  float* out;
  char* hb;                    // [TT+1][128][64][16B]  (group, hi4|lo4)
  char* xb;                    // [TT][128][64][16B]    pre-split emb rows
  float* psum;                 // [TT][NLOG][64] f32 (t-unique)
  unsigned long long* pmax;    // [TT][NLOG][64] u64
  float* inv;                  // [TT][BB]
  int* ctr;                    // cd [TT][64][16] | ld [TT][128][16] | rn [TT][64][16]
};

// rebuild hi/lo bf16x8 for (tt,row,k-frag kk) from two 16B loads
__device__ inline void loadH(const char* hb, int tt, int row, int kk,
                             bf16x8& ah, bf16x8& al) {
  size_t off = (((size_t)tt * 128 + (kk >> 2)) * 64 + row) * 16;
  uint4 v0 = *(const uint4*)(hb + off);
  uint4 v1 = *(const uint4*)(hb + off + 1024);   // next group
  union { unsigned u[4]; bf16x8 v; } A, B;
  A.u[0] = v0.x; A.u[1] = v0.y; A.u[2] = v1.x; A.u[3] = v1.y;
  B.u[0] = v0.z; B.u[1] = v0.w; B.u[2] = v1.z; B.u[3] = v1.w;
  ah = A.v; al = B.v;
}

struct SMCell { __bf16 Ch[16][1042]; __bf16 Cl[16][1042]; float pre[64][17]; };
struct SMLog  { __bf16 Bh[32][522];  __bf16 Bl[32][522]; };
union SMU { SMCell c; SMLog l; };

#define CD_STRIDE (64 * 16)    // 1024 ints per step
#define LD_STRIDE (128 * 16)   // 2048 ints per step
#define RN_STRIDE (64 * 16)    // 1024 ints per step
#define CTR_TOTAL (TT * (CD_STRIDE + LD_STRIDE + RN_STRIDE))   // 131,072 ints

__global__ __launch_bounds__(256) void k_init(
    const float* __restrict__ h0,
    char* __restrict__ hb, int* __restrict__ ctrs) {
  int i = blockIdx.x * 256 + threadIdx.x;   // 128 blocks = BB*HID threads
  int row = i >> 9, k = i & 511, g = k >> 2, q = k & 3;
  float h = h0[i];
  __bf16 hi, lo; split2(h, hi, lo);
  char* base = hb + (((size_t)g) * 64 + row) * 16;   // t=0
  ((unsigned short*)base)[q]       = __builtin_bit_cast(unsigned short, hi);
  ((unsigned short*)(base + 8))[q] = __builtin_bit_cast(unsigned short, lo);
  for (int j = i; j < CTR_TOTAL; j += 128 * 256) ctrs[j] = 0;
}

__global__ __launch_bounds__(256, 2) void k_main(Params p) {
  __shared__ SMU sm;
  __shared__ float red_s[4];
  __shared__ unsigned long long red_m[4];
  __shared__ unsigned sh_tok;
  const int bid = blockIdx.x, tid = threadIdx.x;
  const int lane = tid & 63, wid = tid >> 6;

  int* cd0 = p.ctr;                             // [TT][64][16]
  int* ld0 = p.ctr + TT * CD_STRIDE;            // [TT][128][16]
  int* rn0 = p.ctr + TT * (CD_STRIDE + LD_STRIDE); // [TT][64][16]

  // ======================= CELL blocks 0..127 =======================
  if (bid < NCELL) {
    const int n0 = bid * 4;
    const float* WH[4] = {p.Whi, p.Whf, p.Who, p.Whz};
    const float* WX[4] = {p.Wxi, p.Wxf, p.Wxo, p.Wxz};

    // one-time stage: 16 rows (gate g, col j) x K=1024 (h:0..511, x:512..1023)
    #pragma unroll
    for (int i2 = 0; i2 < 16; i2++) {
      int e = tid + i2 * 256;          // e = k*4 + g
      int k = e >> 2, g = e & 3;
      const float* src = (k < HID) ? (WH[g] + (size_t)k * HID + n0)
                                   : (WX[g] + (size_t)(k - HID) * HID + n0);
      float4 w = *(const float4*)src;
      #pragma unroll
      for (int j = 0; j < 4; j++) {
        __bf16 hi, lo; split2(((const float*)&w)[j], hi, lo);
        sm.c.Ch[g * 4 + j][k] = hi;
        sm.c.Cl[g * 4 + j][k] = lo;
      }
    }
    __syncthreads();

    const int row  = wid * 16 + (lane & 15);
    const int brow = lane & 15;
    const int rl0  = tid >> 2, nn0 = n0 + (tid & 3);
    float creg = p.c0[rl0 * HID + nn0];   // persistent cell state in register

    for (int t = 0; t < TT; t++) {
      if (t > 0) spinN<64>(cd0 + (t - 1) * CD_STRIDE, NCELL);  // h[t] ready

      f32x4 accA = {0.f, 0.f, 0.f, 0.f};
      f32x4 accB = {0.f, 0.f, 0.f, 0.f};

      // h-part FIRST (needs only cd[t-1]) — overlaps logits/reduce of t-1
      #pragma unroll
      for (int ks = 0; ks < 16; ks++) {
        int kk = ks * 32 + (lane >> 4) * 8;
        bf16x8 ah, al;
        loadH(p.hb, t, row, kk, ah, al);
        bf16x8 bh = *(const bf16x8*)&sm.c.Ch[brow][kk];
        bf16x8 bl = *(const bf16x8*)&sm.c.Cl[brow][kk];
        accA = __builtin_amdgcn_mfma_f32_16x16x32_bf16(ah, bh, accA, 0, 0, 0);
        accB = __builtin_amdgcn_mfma_f32_16x16x32_bf16(ah, bl, accB, 0, 0, 0);
        accB = __builtin_amdgcn_mfma_f32_16x16x32_bf16(al, bh, accB, 0, 0, 0);
        accA = __builtin_amdgcn_mfma_f32_16x16x32_bf16(al, bl, accA, 0, 0, 0);
      }

      // x-part: t==0 from input x; else pre-split xb[t-1] (written by reducers)
      if (t == 0) {
        const float* xrow = p.x + (size_t)row * TT * XD;
        #pragma unroll
        for (int ks = 16; ks < 32; ks++) {
          int kk = ks * 32 + (lane >> 4) * 8;        // 512..1016
          const float* xp = xrow + (kk - HID);
          float4 w0 = *(const float4*)(xp);
          float4 w1 = *(const float4*)(xp + 4);
          bf16x8 ah, al;
          #pragma unroll
          for (int j = 0; j < 4; j++) {
            __bf16 hi, lo;
            split2(((const float*)&w0)[j], hi, lo); ah[j] = hi; al[j] = lo;
            split2(((const float*)&w1)[j], hi, lo); ah[4 + j] = hi; al[4 + j] = lo;
          }
          bf16x8 bh = *(const bf16x8*)&sm.c.Ch[brow][kk];
          bf16x8 bl = *(const bf16x8*)&sm.c.Cl[brow][kk];
          accA = __builtin_amdgcn_mfma_f32_16x16x32_bf16(ah, bh, accA, 0, 0, 0);
          accB = __builtin_amdgcn_mfma_f32_16x16x32_bf16(ah, bl, accB, 0, 0, 0);
          accB = __builtin_amdgcn_mfma_f32_16x16x32_bf16(al, bh, accB, 0, 0, 0);
          accA = __builtin_amdgcn_mfma_f32_16x16x32_bf16(al, bl, accA, 0, 0, 0);
        }
      } else {
        spinN<64>(rn0 + (t - 1) * RN_STRIDE, BB);    // xb[t-1] published
        #pragma unroll
        for (int ks = 16; ks < 32; ks++) {
          int kk = ks * 32 + (lane >> 4) * 8;
          bf16x8 ah, al;
          loadH(p.xb, t - 1, row, kk - 512, ah, al);
          bf16x8 bh = *(const bf16x8*)&sm.c.Ch[brow][kk];
          bf16x8 bl = *(const bf16x8*)&sm.c.Cl[brow][kk];
          accA = __builtin_amdgcn_mfma_f32_16x16x32_bf16(ah, bh, accA, 0, 0, 0);
          accB = __builtin_amdgcn_mfma_f32_16x16x32_bf16(ah, bl, accB, 0, 0, 0);
          accB = __builtin_amdgcn_mfma_f32_16x16x32_bf16(al, bh, accB, 0, 0, 0);
          accA = __builtin_amdgcn_mfma_f32_16x16x32_bf16(al, bl, accA, 0, 0, 0);
        }
      }

      #pragma unroll
      for (int j = 0; j < 4; j++)
        sm.c.pre[wid * 16 + (lane >> 4) * 4 + j][lane & 15] = accA[j] + accB[j];
      __syncthreads();

      float cnv;
      {
        float pi = sm.c.pre[rl0][(tid & 3)]      + p.bi[nn0];
        float pf = sm.c.pre[rl0][4 + (tid & 3)]  + p.bfg[nn0];
        float pq = sm.c.pre[rl0][8 + (tid & 3)]  + p.bo[nn0];
        float pz = sm.c.pre[rl0][12 + (tid & 3)] + p.bz[nn0];
        float ig = 1.f / (1.f + expf(-pi));
        float fg = 1.f / (1.f + expf(-pf));
        float og = 1.f / (1.f + expf(-pq));
        float zg = tanhf(pz);
        float cn = ig * zg + fg * creg;
        creg = cn;
        float hn = og * tanhf(cn);
        __bf16 hh, hl; split2(hn, hh, hl);
        unsigned hhu = (unsigned)__builtin_bit_cast(unsigned short, hh);
        unsigned hlu = (unsigned)__builtin_bit_cast(unsigned short, hl);
        unsigned hi1 = __shfl_down(hhu, 1), hi2 = __shfl_down(hhu, 2),
                 hi3 = __shfl_down(hhu, 3);
        unsigned lo1 = __shfl_down(hlu, 1), lo2 = __shfl_down(hlu, 2),
                 lo3 = __shfl_down(hlu, 3);
        if ((tid & 3) == 0) {
          u32x4 d = { hhu | (hi1 << 16), hi2 | (hi3 << 16),
                      hlu | (lo1 << 16), lo2 | (lo3 << 16) };
          st_wt16(p.hb + (((size_t)(t + 1) * 128 + bid) * 64 + rl0) * 16, d);
        }
        cnv = cn;
      }
      publishN<64>(cd0 + t * CD_STRIDE);   // drains only the h wt-stores
      // c-state store AFTER publish: HBM store latency off the chain
      p.out[(size_t)BB * TT * NV + (size_t)rl0 * TT * HID + (size_t)t * HID + nn0] = cnv;
    }
    return;
  }

  // ======================= LOGITS blocks 128..440 =======================
  if (bid < NORMB) {
    const int lb = bid - LOGB;
    const int v0 = lb * VB;
    const int row = wid * 16 + (lane & 15);

    float bcar[2];
    float evp[2][4];   // previous step's exp values (y written one step late)

    auto stageW = [&](int widx) {
      const float* W = p.W_lin + (size_t)widx * HID * NV;
      float4 v[16];
      #pragma unroll
      for (int i2 = 0; i2 < 16; i2++) {
        int e = tid + i2 * 256;          // e = k*8 + pp
        int k = e >> 3, pp = e & 7;
        v[i2] = *(const float4*)(W + (size_t)k * NV + v0 + pp * 4);
      }
      const float* bn = p.b_lin + (size_t)widx * NV;
      bcar[0] = bn[v0 + (lane & 15)];
      bcar[1] = bn[v0 + 16 + (lane & 15)];   // may over-read; masked later
      #pragma unroll
      for (int i2 = 0; i2 < 16; i2++) {
        int e = tid + i2 * 256;
        int k = e >> 3, pp = e & 7;
        #pragma unroll
        for (int j = 0; j < 4; j++) {
          __bf16 hi, lo; split2(((const float*)&v[i2])[j], hi, lo);
          sm.l.Bh[pp * 4 + j][k] = hi;
          sm.l.Bl[pp * 4 + j][k] = lo;
        }
      }
    };

    stageW(0);   // logits(0) uses lidx=0

    for (int t = 0; t < TT; t++) {
      spinN<64>(cd0 + t * CD_STRIDE, NCELL);  // h[t+1] ready; barrier covers LDS

      f32x4 acc[2][2] = {};
      #pragma unroll
      for (int ks = 0; ks < 16; ks++) {
        int kk = ks * 32 + (lane >> 4) * 8;
        bf16x8 ah, al;
        loadH(p.hb, t + 1, row, kk, ah, al);
        #pragma unroll
        for (int vt = 0; vt < 2; vt++) {
          int rrow = vt * 16 + (lane & 15);
          bf16x8 bh = *(const bf16x8*)&sm.l.Bh[rrow][kk];
          bf16x8 bl = *(const bf16x8*)&sm.l.Bl[rrow][kk];
          acc[vt][0] = __builtin_amdgcn_mfma_f32_16x16x32_bf16(ah, bh, acc[vt][0], 0, 0, 0);
          acc[vt][1] = __builtin_amdgcn_mfma_f32_16x16x32_bf16(ah, bl, acc[vt][1], 0, 0, 0);
          acc[vt][1] = __builtin_amdgcn_mfma_f32_16x16x32_bf16(al, bh, acc[vt][1], 0, 0, 0);
          acc[vt][0] = __builtin_amdgcn_mfma_f32_16x16x32_bf16(al, bl, acc[vt][0], 0, 0, 0);
        }
      }

      float ev[2][4];
      float rsum[4] = {0.f, 0.f, 0.f, 0.f};
      unsigned long long rmax[4] = {0ULL, 0ULL, 0ULL, 0ULL};
      #pragma unroll
      for (int vt = 0; vt < 2; vt++) {
        int v = v0 + vt * 16 + (lane & 15);
        bool ok = (v < NV);
        float bb = ok ? bcar[vt] : 0.f;
        #pragma unroll
        for (int j = 0; j < 4; j++) {
          float logit = acc[vt][0][j] + acc[vt][1][j] + bb;
          float e = ok ? expf(logit) : 0.f;   // no max-subtract: |logit| small
          ev[vt][j] = e;
          rsum[j] += e;
          if (ok) {
            unsigned long long pk = packkey(logit, v);
            if (pk > rmax[j]) rmax[j] = pk;
          }
        }
      }

      #pragma unroll
      for (int off = 1; off < 16; off <<= 1) {
        #pragma unroll
        for (int j = 0; j < 4; j++) {
          rsum[j] += __shfl_xor(rsum[j], off);
          unsigned long long o = shflxor64(rmax[j], off);
          if (o > rmax[j]) rmax[j] = o;
        }
      }
      if ((lane & 15) == 0) {
        int rbase = wid * 16 + (lane >> 4) * 4;
        union { float f[4]; u32x4 u; } S;
        S.f[0] = rsum[0]; S.f[1] = rsum[1]; S.f[2] = rsum[2]; S.f[3] = rsum[3];
        st_wt16(&p.psum[((size_t)t * NLOG + lb) * 64 + rbase], S.u);
        u32x4 M0 = { (unsigned)rmax[0], (unsigned)(rmax[0] >> 32),
                     (unsigned)rmax[1], (unsigned)(rmax[1] >> 32) };
        u32x4 M1 = { (unsigned)rmax[2], (unsigned)(rmax[2] >> 32),
                     (unsigned)rmax[3], (unsigned)(rmax[3] >> 32) };
        st_wt16(&p.pmax[((size_t)t * NLOG + lb) * 64 + rbase], M0);
        st_wt16(&p.pmax[((size_t)t * NLOG + lb) * 64 + rbase + 2], M1);
      }
      publishN<128>(ld0 + t * LD_STRIDE);  // tiny drain: 3 wide stores

      if (t < TT - 1) stageW(t);           // overlaps reduce(t) + cell(t+1)

      // write y(t-1): cd[t] implies rn[t-1], so inv[t-1] is valid (plain read)
      if (t > 0) {
        float invr[4];
        #pragma unroll
        for (int j = 0; j < 4; j++)
          invr[j] = p.inv[(size_t)(t - 1) * BB + wid * 16 + (lane >> 4) * 4 + j];
        #pragma unroll
        for (int vt = 0; vt < 2; vt++) {
          int v = v0 + vt * 16 + (lane & 15);
          if (v < NV) {
            #pragma unroll
            for (int j = 0; j < 4; j++) {
              int r = wid * 16 + (lane >> 4) * 4 + j;
              p.out[(size_t)r * TT * NV + (size_t)(t - 1) * NV + v] = evp[vt][j] * invr[j];
            }
          }
        }
      }
      #pragma unroll
      for (int vt = 0; vt < 2; vt++)
        #pragma unroll
        for (int j = 0; j < 4; j++) evp[vt][j] = ev[vt][j];
    }

    // final y(31)
    spinN<64>(rn0 + (TT - 1) * RN_STRIDE, BB);
    float invr[4];
    #pragma unroll
    for (int j = 0; j < 4; j++)
      invr[j] = p.inv[(size_t)(TT - 1) * BB + wid * 16 + (lane >> 4) * 4 + j];
    #pragma unroll
    for (int vt = 0; vt < 2; vt++) {
      int v = v0 + vt * 16 + (lane & 15);
      if (v < NV) {
        #pragma unroll
        for (int j = 0; j < 4; j++) {
          int r = wid * 16 + (lane >> 4) * 4 + j;
          p.out[(size_t)r * TT * NV + (size_t)(TT - 1) * NV + v] = evp[vt][j] * invr[j];
        }
      }
    }
    return;
  }

  // ================= REDUCE blocks 441..504 (one per row) =============
  if (bid < NORMB + BB) {
    const int r = bid - NORMB;
    for (int t = 0; t < TT; t++) {
      spinN<128>(ld0 + t * LD_STRIDE, NLOG);

      float s = 0.f; unsigned long long m = 0ULL;
      for (int i = tid; i < NLOG; i += 256) {
        s += p.psum[((size_t)t * NLOG + i) * 64 + r];
        unsigned long long v = p.pmax[((size_t)t * NLOG + i) * 64 + r];
        if (v > m) m = v;
      }
      #pragma unroll
      for (int off = 1; off < 64; off <<= 1) {
        s += __shfl_xor(s, off);
        unsigned long long o = shflxor64(m, off);
        if (o > m) m = o;
      }
      if (lane == 0) { red_s[wid] = s; red_m[wid] = m; }
      __syncthreads();
      if (tid == 0) {
        s = red_s[0] + red_s[1] + red_s[2] + red_s[3];
        m = red_m[0];
        if (red_m[1] > m) m = red_m[1];
        if (red_m[2] > m) m = red_m[2];
        if (red_m[3] > m) m = red_m[3];
        sh_tok = 0xFFFFFFFFu - (unsigned)(m & 0xFFFFFFFFull);
        __hip_atomic_store((unsigned*)&p.inv[(size_t)t * BB + r],
                           __builtin_bit_cast(unsigned, 1.0f / s),
                           __ATOMIC_RELAXED, __HIP_MEMORY_SCOPE_AGENT);
      }
      __syncthreads();

      // pre-split next-step x row: emb[tok] -> xb[t] (hi4|lo4 16B groups)
      unsigned tokv = sh_tok;
      if (tid < 128) {
        float4 w = *(const float4*)(p.emb + (size_t)tokv * XD + tid * 4);
        unsigned h[4], l[4];
        #pragma unroll
        for (int j = 0; j < 4; j++) {
          __bf16 hi, lo; split2(((const float*)&w)[j], hi, lo);
          h[j] = (unsigned)__builtin_bit_cast(unsigned short, hi);
          l[j] = (unsigned)__builtin_bit_cast(unsigned short, lo);
        }
        u32x4 d = { h[0] | (h[1] << 16), h[2] | (h[3] << 16),
                    l[0] | (l[1] << 16), l[2] | (l[3] << 16) };
        st_wt16(p.xb + (((size_t)t * 128 + tid) * 64 + r) * 16, d);
      }
      publishN<64>(rn0 + t * RN_STRIDE);  // drain inv + xb stores, then bump
      __syncthreads();                    // red_s/red_m/sh_tok reuse safety
    }
    return;
  }
  // blocks 505..511 idle
}

extern "C" void kernel_launch(void* const* d_in, const int* in_sizes, int n_in,
                              void* d_out, int out_size, void* d_ws, size_t ws_size,
                              hipStream_t stream) {
  const float* x     = (const float*)d_in[0];
  const float* h0    = (const float*)d_in[1];
  const float* c0    = (const float*)d_in[2];
  const float* W_hi  = (const float*)d_in[3];
  const float* W_xi  = (const float*)d_in[4];
  const float* b_i   = (const float*)d_in[5];
  const float* W_hf  = (const float*)d_in[6];
  const float* W_xf  = (const float*)d_in[7];
  const float* b_f   = (const float*)d_in[8];
  const float* W_ho  = (const float*)d_in[9];
  const float* W_xo  = (const float*)d_in[10];
  const float* b_o   = (const float*)d_in[11];
  const float* W_hz  = (const float*)d_in[12];
  const float* W_xz  = (const float*)d_in[13];
  const float* b_z   = (const float*)d_in[14];
  const float* W_lin = (const float*)d_in[15];
  const float* b_lin = (const float*)d_in[16];
  const float* emb   = (const float*)d_in[17];

  float* out = (float*)d_out;
  char* ws = (char*)d_ws;
  // layout (bytes):
  char*   hb   = ws;                                              // 33*128*64*16 = 4,325,376
  char*   xb   = ws + 4325376;                                    // 32*128*64*16 = 4,194,304
  float*  psum = (float*)(ws + 8519680);                          // 32*313*64*4 = 2,564,096
  unsigned long long* pmax = (unsigned long long*)(ws + 11083776);// 32*313*64*8 = 5,128,192
  float*  inv  = (float*)(ws + 16211968);                         //        8,192
  int*    ctrs = (int*)(ws + 16220160);                           //      524,288

  k_init<<<128, 256, 0, stream>>>(h0, hb, ctrs);

  Params P;
  P.x = x; P.emb = emb; P.c0 = c0;
  P.Whi = W_hi; P.Whf = W_hf; P.Who = W_ho; P.Whz = W_hz;
  P.Wxi = W_xi; P.Wxf = W_xf; P.Wxo = W_xo; P.Wxz = W_xz;
  P.bi = b_i; P.bfg = b_f; P.bo = b_o; P.bz = b_z;
  P.W_lin = W_lin; P.b_lin = b_lin;
  P.out = out;
  P.hb = hb; P.xb = xb;
  P.psum = psum; P.pmax = pmax; P.inv = inv;
  P.ctr = ctrs;

  k_main<<<GRID, 256, 0, stream>>>(P);
}

// Round 20
// 711.599 us; speedup vs baseline: 1.2140x; 1.0039x over previous
//
#include <hip/hip_runtime.h>
#include <hip/hip_bf16.h>
#include <stdint.h>

#define BB 64
#define TT 32
#define HID 512
#define XD  512
#define NV  10000

#define GRID   512
#define NCELL  128
#define VB     32
#define NLOG   313       // ceil(10000/32)
#define LOGB   128       // logits blocks 128..440
#define NORMB  441       // reduce blocks 441..504 (one per batch row)

typedef __bf16 bf16x8 __attribute__((ext_vector_type(8)));
typedef float  f32x4  __attribute__((ext_vector_type(4)));
typedef unsigned u32x4 __attribute__((ext_vector_type(4)));

__device__ inline void split2(float w, __bf16& hi, __bf16& lo) {
  hi = (__bf16)w;
  lo = (__bf16)(w - (float)hi);
}

__device__ inline unsigned long long shflxor64(unsigned long long v, int m) {
  unsigned lo = (unsigned)(v & 0xFFFFFFFFull);
  unsigned hi = (unsigned)(v >> 32);
  lo = __shfl_xor(lo, m);
  hi = __shfl_xor(hi, m);
  return ((unsigned long long)hi << 32) | lo;
}

// monotonic packing of (logit, vocab index); larger u64 = larger logit,
// ties broken toward SMALLER index (matches jnp.argmax first-occurrence).
__device__ inline unsigned long long packkey(float f, int v) {
  unsigned ub = __float_as_uint(f);
  unsigned key = (ub & 0x80000000u) ? ~ub : (ub | 0x80000000u);
  return ((unsigned long long)key << 32) | (unsigned)(0xFFFFFFFFu - (unsigned)v);
}

// device-coherent (write-through to LLC) 16B store
__device__ inline void st_wt16(void* addr, u32x4 d) {
  asm volatile("global_store_dwordx4 %0, %1, off sc0 sc1"
               :: "v"(addr), "v"(d) : "memory");
}

// ---- sync: NL-line-spread relaxed counters, WAVE-PARALLEL poll ----
// ONE producer per 64B line (slot = producer index) -> zero RMW contention.
// Lane i polls lines i, i+64, ... (NL/64 wave loads per round), butterfly-sum.
template<int NL>
__device__ inline void spinN(int* base, int target) {
  if (threadIdx.x < 64) {
    int lane = threadIdx.x;
    int s;
    do {
      int v = 0;
      #pragma unroll
      for (int i = 0; i < (NL + 63) / 64; i++) {
        int idx = lane + i * 64;
        if (NL % 64 == 0 || idx < NL)
          v += __hip_atomic_load(base + idx * 16, __ATOMIC_RELAXED,
                                 __HIP_MEMORY_SCOPE_AGENT);
      }
      #pragma unroll
      for (int m = 1; m < 64; m <<= 1) v += __shfl_xor(v, m);
      s = v;
      if (s < target) __builtin_amdgcn_s_sleep(1);
    } while (s < target);
  }
  __syncthreads();
}
// drain write-through stores (vmcnt 0), barrier, one relaxed bump on OWN line
__device__ inline void publishSlot(int* slot) {
  asm volatile("s_waitcnt vmcnt(0)" ::: "memory");
  __syncthreads();
  if (threadIdx.x == 0)
    __hip_atomic_fetch_add(slot, 1, __ATOMIC_RELAXED, __HIP_MEMORY_SCOPE_AGENT);
}

struct Params {
  const float *x, *emb, *c0;
  const float *Whi, *Whf, *Who, *Whz;
  const float *Wxi, *Wxf, *Wxo, *Wxz;
  const float *bi, *bfg, *bo, *bz;
  const float *W_lin, *b_lin;
  float* out;
  char* hb;                    // [TT+1][128][64][16B]  (group, hi4|lo4)
  char* xb;                    // [TT][128][64][16B]    pre-split emb rows
  float* psum;                 // [TT][NLOG][64] f32 (t-unique)
  unsigned long long* pmax;    // [TT][NLOG][64] u64
  float* inv;                  // [TT][BB]
  int* ctr;                    // cd [TT][128][16] | ld [TT][320][16] | rn [TT][64][16]
};

// rebuild hi/lo bf16x8 for (tt,row,k-frag kk) from two 16B loads
__device__ inline void loadH(const char* hb, int tt, int row, int kk,
                             bf16x8& ah, bf16x8& al) {
  size_t off = (((size_t)tt * 128 + (kk >> 2)) * 64 + row) * 16;
  uint4 v0 = *(const uint4*)(hb + off);
  uint4 v1 = *(const uint4*)(hb + off + 1024);   // next group
  union { unsigned u[4]; bf16x8 v; } A, B;
  A.u[0] = v0.x; A.u[1] = v0.y; A.u[2] = v1.x; A.u[3] = v1.y;
  B.u[0] = v0.z; B.u[1] = v0.w; B.u[2] = v1.z; B.u[3] = v1.w;
  ah = A.v; al = B.v;
}

struct SMCell { __bf16 Ch[16][1042]; __bf16 Cl[16][1042]; float pre[64][17]; };
struct SMLog  { __bf16 Bh[32][522];  __bf16 Bl[32][522]; };
union SMU { SMCell c; SMLog l; };

#define CD_STRIDE (128 * 16)   // 2048 ints per step
#define LD_STRIDE (320 * 16)   // 5120 ints per step
#define RN_STRIDE (64 * 16)    // 1024 ints per step
#define CTR_TOTAL (TT * (CD_STRIDE + LD_STRIDE + RN_STRIDE))   // 262,144 ints

__global__ __launch_bounds__(256) void k_init(
    const float* __restrict__ h0,
    char* __restrict__ hb, int* __restrict__ ctrs) {
  int i = blockIdx.x * 256 + threadIdx.x;   // 128 blocks = BB*HID threads
  int row = i >> 9, k = i & 511, g = k >> 2, q = k & 3;
  float h = h0[i];
  __bf16 hi, lo; split2(h, hi, lo);
  char* base = hb + (((size_t)g) * 64 + row) * 16;   // t=0
  ((unsigned short*)base)[q]       = __builtin_bit_cast(unsigned short, hi);
  ((unsigned short*)(base + 8))[q] = __builtin_bit_cast(unsigned short, lo);
  for (int j = i; j < CTR_TOTAL; j += 128 * 256) ctrs[j] = 0;
}

__global__ __launch_bounds__(256, 2) void k_main(Params p) {
  __shared__ SMU sm;
  __shared__ float red_s[4];
  __shared__ unsigned long long red_m[4];
  __shared__ unsigned sh_tok;
  const int bid = blockIdx.x, tid = threadIdx.x;
  const int lane = tid & 63, wid = tid >> 6;

  int* cd0 = p.ctr;                                // [TT][128][16]
  int* ld0 = p.ctr + TT * CD_STRIDE;               // [TT][320][16]
  int* rn0 = p.ctr + TT * (CD_STRIDE + LD_STRIDE); // [TT][64][16]

  // ======================= CELL blocks 0..127 =======================
  if (bid < NCELL) {
    const int n0 = bid * 4;
    const float* WH[4] = {p.Whi, p.Whf, p.Who, p.Whz};
    const float* WX[4] = {p.Wxi, p.Wxf, p.Wxo, p.Wxz};

    // one-time stage: 16 rows (gate g, col j) x K=1024 (h:0..511, x:512..1023)
    #pragma unroll
    for (int i2 = 0; i2 < 16; i2++) {
      int e = tid + i2 * 256;          // e = k*4 + g
      int k = e >> 2, g = e & 3;
      const float* src = (k < HID) ? (WH[g] + (size_t)k * HID + n0)
                                   : (WX[g] + (size_t)(k - HID) * HID + n0);
      float4 w = *(const float4*)src;
      #pragma unroll
      for (int j = 0; j < 4; j++) {
        __bf16 hi, lo; split2(((const float*)&w)[j], hi, lo);
        sm.c.Ch[g * 4 + j][k] = hi;
        sm.c.Cl[g * 4 + j][k] = lo;
      }
    }
    __syncthreads();

    const int row  = wid * 16 + (lane & 15);
    const int brow = lane & 15;
    const int rl0  = tid >> 2, nn0 = n0 + (tid & 3);
    float creg = p.c0[rl0 * HID + nn0];   // persistent cell state in register

    for (int t = 0; t < TT; t++) {
      if (t > 0) spinN<128>(cd0 + (t - 1) * CD_STRIDE, NCELL);  // h[t] ready

      f32x4 accA = {0.f, 0.f, 0.f, 0.f};
      f32x4 accB = {0.f, 0.f, 0.f, 0.f};

      // h-part FIRST (needs only cd[t-1]) — overlaps logits/reduce of t-1
      #pragma unroll
      for (int ks = 0; ks < 16; ks++) {
        int kk = ks * 32 + (lane >> 4) * 8;
        bf16x8 ah, al;
        loadH(p.hb, t, row, kk, ah, al);
        bf16x8 bh = *(const bf16x8*)&sm.c.Ch[brow][kk];
        bf16x8 bl = *(const bf16x8*)&sm.c.Cl[brow][kk];
        accA = __builtin_amdgcn_mfma_f32_16x16x32_bf16(ah, bh, accA, 0, 0, 0);
        accB = __builtin_amdgcn_mfma_f32_16x16x32_bf16(ah, bl, accB, 0, 0, 0);
        accB = __builtin_amdgcn_mfma_f32_16x16x32_bf16(al, bh, accB, 0, 0, 0);
        accA = __builtin_amdgcn_mfma_f32_16x16x32_bf16(al, bl, accA, 0, 0, 0);
      }

      // x-part: t==0 from input x; else pre-split xb[t-1] (written by reducers)
      if (t == 0) {
        const float* xrow = p.x + (size_t)row * TT * XD;
        #pragma unroll
        for (int ks = 16; ks < 32; ks++) {
          int kk = ks * 32 + (lane >> 4) * 8;        // 512..1016
          const float* xp = xrow + (kk - HID);
          float4 w0 = *(const float4*)(xp);
          float4 w1 = *(const float4*)(xp + 4);
          bf16x8 ah, al;
          #pragma unroll
          for (int j = 0; j < 4; j++) {
            __bf16 hi, lo;
            split2(((const float*)&w0)[j], hi, lo); ah[j] = hi; al[j] = lo;
            split2(((const float*)&w1)[j], hi, lo); ah[4 + j] = hi; al[4 + j] = lo;
          }
          bf16x8 bh = *(const bf16x8*)&sm.c.Ch[brow][kk];
          bf16x8 bl = *(const bf16x8*)&sm.c.Cl[brow][kk];
          accA = __builtin_amdgcn_mfma_f32_16x16x32_bf16(ah, bh, accA, 0, 0, 0);
          accB = __builtin_amdgcn_mfma_f32_16x16x32_bf16(ah, bl, accB, 0, 0, 0);
          accB = __builtin_amdgcn_mfma_f32_16x16x32_bf16(al, bh, accB, 0, 0, 0);
          accA = __builtin_amdgcn_mfma_f32_16x16x32_bf16(al, bl, accA, 0, 0, 0);
        }
      } else {
        spinN<64>(rn0 + (t - 1) * RN_STRIDE, BB);    // xb[t-1] published
        #pragma unroll
        for (int ks = 16; ks < 32; ks++) {
          int kk = ks * 32 + (lane >> 4) * 8;
          bf16x8 ah, al;
          loadH(p.xb, t - 1, row, kk - 512, ah, al);
          bf16x8 bh = *(const bf16x8*)&sm.c.Ch[brow][kk];
          bf16x8 bl = *(const bf16x8*)&sm.c.Cl[brow][kk];
          accA = __builtin_amdgcn_mfma_f32_16x16x32_bf16(ah, bh, accA, 0, 0, 0);
          accB = __builtin_amdgcn_mfma_f32_16x16x32_bf16(ah, bl, accB, 0, 0, 0);
          accB = __builtin_amdgcn_mfma_f32_16x16x32_bf16(al, bh, accB, 0, 0, 0);
          accA = __builtin_amdgcn_mfma_f32_16x16x32_bf16(al, bl, accA, 0, 0, 0);
        }
      }

      #pragma unroll
      for (int j = 0; j < 4; j++)
        sm.c.pre[wid * 16 + (lane >> 4) * 4 + j][lane & 15] = accA[j] + accB[j];
      __syncthreads();

      float cnv;
      {
        float pi = sm.c.pre[rl0][(tid & 3)]      + p.bi[nn0];
        float pf = sm.c.pre[rl0][4 + (tid & 3)]  + p.bfg[nn0];
        float pq = sm.c.pre[rl0][8 + (tid & 3)]  + p.bo[nn0];
        float pz = sm.c.pre[rl0][12 + (tid & 3)] + p.bz[nn0];
        float ig = 1.f / (1.f + expf(-pi));
        float fg = 1.f / (1.f + expf(-pf));
        float og = 1.f / (1.f + expf(-pq));
        float zg = tanhf(pz);
        float cn = ig * zg + fg * creg;
        creg = cn;
        float hn = og * tanhf(cn);
        __bf16 hh, hl; split2(hn, hh, hl);
        unsigned hhu = (unsigned)__builtin_bit_cast(unsigned short, hh);
        unsigned hlu = (unsigned)__builtin_bit_cast(unsigned short, hl);
        unsigned hi1 = __shfl_down(hhu, 1), hi2 = __shfl_down(hhu, 2),
                 hi3 = __shfl_down(hhu, 3);
        unsigned lo1 = __shfl_down(hlu, 1), lo2 = __shfl_down(hlu, 2),
                 lo3 = __shfl_down(hlu, 3);
        if ((tid & 3) == 0) {
          u32x4 d = { hhu | (hi1 << 16), hi2 | (hi3 << 16),
                      hlu | (lo1 << 16), lo2 | (lo3 << 16) };
          st_wt16(p.hb + (((size_t)(t + 1) * 128 + bid) * 64 + rl0) * 16, d);
        }
        cnv = cn;
      }
      publishSlot(cd0 + t * CD_STRIDE + bid * 16);  // own line, no contention
      // c-state store AFTER publish: HBM store latency off the chain
      p.out[(size_t)BB * TT * NV + (size_t)rl0 * TT * HID + (size_t)t * HID + nn0] = cnv;
    }
    return;
  }

  // ======================= LOGITS blocks 128..440 =======================
  if (bid < NORMB) {
    const int lb = bid - LOGB;
    const int v0 = lb * VB;
    const int row = wid * 16 + (lane & 15);

    float bcar[2];
    float evp[2][4];   // previous step's exp values (y written one step late)

    auto stageW = [&](int widx) {
      const float* W = p.W_lin + (size_t)widx * HID * NV;
      float4 v[16];
      #pragma unroll
      for (int i2 = 0; i2 < 16; i2++) {
        int e = tid + i2 * 256;          // e = k*8 + pp
        int k = e >> 3, pp = e & 7;
        v[i2] = *(const float4*)(W + (size_t)k * NV + v0 + pp * 4);
      }
      const float* bn = p.b_lin + (size_t)widx * NV;
      bcar[0] = bn[v0 + (lane & 15)];
      bcar[1] = bn[v0 + 16 + (lane & 15)];   // may over-read; masked later
      #pragma unroll
      for (int i2 = 0; i2 < 16; i2++) {
        int e = tid + i2 * 256;
        int k = e >> 3, pp = e & 7;
        #pragma unroll
        for (int j = 0; j < 4; j++) {
          __bf16 hi, lo; split2(((const float*)&v[i2])[j], hi, lo);
          sm.l.Bh[pp * 4 + j][k] = hi;
          sm.l.Bl[pp * 4 + j][k] = lo;
        }
      }
    };

    stageW(0);   // logits(0) uses lidx=0

    for (int t = 0; t < TT; t++) {
      spinN<128>(cd0 + t * CD_STRIDE, NCELL);  // h[t+1] ready; barrier covers LDS

      f32x4 acc[2][2] = {};
      #pragma unroll
      for (int ks = 0; ks < 16; ks++) {
        int kk = ks * 32 + (lane >> 4) * 8;
        bf16x8 ah, al;
        loadH(p.hb, t + 1, row, kk, ah, al);
        #pragma unroll
        for (int vt = 0; vt < 2; vt++) {
          int rrow = vt * 16 + (lane & 15);
          bf16x8 bh = *(const bf16x8*)&sm.l.Bh[rrow][kk];
          bf16x8 bl = *(const bf16x8*)&sm.l.Bl[rrow][kk];
          acc[vt][0] = __builtin_amdgcn_mfma_f32_16x16x32_bf16(ah, bh, acc[vt][0], 0, 0, 0);
          acc[vt][1] = __builtin_amdgcn_mfma_f32_16x16x32_bf16(ah, bl, acc[vt][1], 0, 0, 0);
          acc[vt][1] = __builtin_amdgcn_mfma_f32_16x16x32_bf16(al, bh, acc[vt][1], 0, 0, 0);
          acc[vt][0] = __builtin_amdgcn_mfma_f32_16x16x32_bf16(al, bl, acc[vt][0], 0, 0, 0);
        }
      }

      float ev[2][4];
      float rsum[4] = {0.f, 0.f, 0.f, 0.f};
      unsigned long long rmax[4] = {0ULL, 0ULL, 0ULL, 0ULL};
      #pragma unroll
      for (int vt = 0; vt < 2; vt++) {
        int v = v0 + vt * 16 + (lane & 15);
        bool ok = (v < NV);
        float bb = ok ? bcar[vt] : 0.f;
        #pragma unroll
        for (int j = 0; j < 4; j++) {
          float logit = acc[vt][0][j] + acc[vt][1][j] + bb;
          float e = ok ? expf(logit) : 0.f;   // no max-subtract: |logit| small
          ev[vt][j] = e;
          rsum[j] += e;
          if (ok) {
            unsigned long long pk = packkey(logit, v);
            if (pk > rmax[j]) rmax[j] = pk;
          }
        }
      }

      #pragma unroll
      for (int off = 1; off < 16; off <<= 1) {
        #pragma unroll
        for (int j = 0; j < 4; j++) {
          rsum[j] += __shfl_xor(rsum[j], off);
          unsigned long long o = shflxor64(rmax[j], off);
          if (o > rmax[j]) rmax[j] = o;
        }
      }
      if ((lane & 15) == 0) {
        int rbase = wid * 16 + (lane >> 4) * 4;
        union { float f[4]; u32x4 u; } S;
        S.f[0] = rsum[0]; S.f[1] = rsum[1]; S.f[2] = rsum[2]; S.f[3] = rsum[3];
        st_wt16(&p.psum[((size_t)t * NLOG + lb) * 64 + rbase], S.u);
        u32x4 M0 = { (unsigned)rmax[0], (unsigned)(rmax[0] >> 32),
                     (unsigned)rmax[1], (unsigned)(rmax[1] >> 32) };
        u32x4 M1 = { (unsigned)rmax[2], (unsigned)(rmax[2] >> 32),
                     (unsigned)rmax[3], (unsigned)(rmax[3] >> 32) };
        st_wt16(&p.pmax[((size_t)t * NLOG + lb) * 64 + rbase], M0);
        st_wt16(&p.pmax[((size_t)t * NLOG + lb) * 64 + rbase + 2], M1);
      }
      publishSlot(ld0 + t * LD_STRIDE + lb * 16);  // own line, no contention

      if (t < TT - 1) stageW(t);           // overlaps reduce(t) + cell(t+1)

      // write y(t-1): cd[t] implies rn[t-1], so inv[t-1] is valid (plain read)
      if (t > 0) {
        float invr[4];
        #pragma unroll
        for (int j = 0; j < 4; j++)
          invr[j] = p.inv[(size_t)(t - 1) * BB + wid * 16 + (lane >> 4) * 4 + j];
        #pragma unroll
        for (int vt = 0; vt < 2; vt++) {
          int v = v0 + vt * 16 + (lane & 15);
          if (v < NV) {
            #pragma unroll
            for (int j = 0; j < 4; j++) {
              int r = wid * 16 + (lane >> 4) * 4 + j;
              p.out[(size_t)r * TT * NV + (size_t)(t - 1) * NV + v] = evp[vt][j] * invr[j];
            }
          }
        }
      }
      #pragma unroll
      for (int vt = 0; vt < 2; vt++)
        #pragma unroll
        for (int j = 0; j < 4; j++) evp[vt][j] = ev[vt][j];
    }

    // final y(31)
    spinN<64>(rn0 + (TT - 1) * RN_STRIDE, BB);
    float invr[4];
    #pragma unroll
    for (int j = 0; j < 4; j++)
      invr[j] = p.inv[(size_t)(TT - 1) * BB + wid * 16 + (lane >> 4) * 4 + j];
    #pragma unroll
    for (int vt = 0; vt < 2; vt++) {
      int v = v0 + vt * 16 + (lane & 15);
      if (v < NV) {
        #pragma unroll
        for (int j = 0; j < 4; j++) {
          int r = wid * 16 + (lane >> 4) * 4 + j;
          p.out[(size_t)r * TT * NV + (size_t)(TT - 1) * NV + v] = evp[vt][j] * invr[j];
        }
      }
    }
    return;
  }

  // ================= REDUCE blocks 441..504 (one per row) =============
  if (bid < NORMB + BB) {
    const int r = bid - NORMB;
    for (int t = 0; t < TT; t++) {
      spinN<320>(ld0 + t * LD_STRIDE, NLOG);

      float s = 0.f; unsigned long long m = 0ULL;
      for (int i = tid; i < NLOG; i += 256) {
        s += p.psum[((size_t)t * NLOG + i) * 64 + r];
        unsigned long long v = p.pmax[((size_t)t * NLOG + i) * 64 + r];
        if (v > m) m = v;
      }
      #pragma unroll
      for (int off = 1; off < 64; off <<= 1) {
        s += __shfl_xor(s, off);
        unsigned long long o = shflxor64(m, off);
        if (o > m) m = o;
      }
      if (lane == 0) { red_s[wid] = s; red_m[wid] = m; }
      __syncthreads();
      if (tid == 0) {
        s = red_s[0] + red_s[1] + red_s[2] + red_s[3];
        m = red_m[0];
        if (red_m[1] > m) m = red_m[1];
        if (red_m[2] > m) m = red_m[2];
        if (red_m[3] > m) m = red_m[3];
        sh_tok = 0xFFFFFFFFu - (unsigned)(m & 0xFFFFFFFFull);
        __hip_atomic_store((unsigned*)&p.inv[(size_t)t * BB + r],
                           __builtin_bit_cast(unsigned, 1.0f / s),
                           __ATOMIC_RELAXED, __HIP_MEMORY_SCOPE_AGENT);
      }
      __syncthreads();

      // pre-split next-step x row: emb[tok] -> xb[t] (hi4|lo4 16B groups)
      unsigned tokv = sh_tok;
      if (tid < 128) {
        float4 w = *(const float4*)(p.emb + (size_t)tokv * XD + tid * 4);
        unsigned h[4], l[4];
        #pragma unroll
        for (int j = 0; j < 4; j++) {
          __bf16 hi, lo; split2(((const float*)&w)[j], hi, lo);
          h[j] = (unsigned)__builtin_bit_cast(unsigned short, hi);
          l[j] = (unsigned)__builtin_bit_cast(unsigned short, lo);
        }
        u32x4 d = { h[0] | (h[1] << 16), h[2] | (h[3] << 16),
                    l[0] | (l[1] << 16), l[2] | (l[3] << 16) };
        st_wt16(p.xb + (((size_t)t * 128 + tid) * 64 + r) * 16, d);
      }
      publishSlot(rn0 + t * RN_STRIDE + r * 16);  // own line, no contention
      __syncthreads();                    // red_s/red_m/sh_tok reuse safety
    }
    return;
  }
  // blocks 505..511 idle
}

extern "C" void kernel_launch(void* const* d_in, const int* in_sizes, int n_in,
                              void* d_out, int out_size, void* d_ws, size_t ws_size,
                              hipStream_t stream) {
  const float* x     = (const float*)d_in[0];
  const float* h0    = (const float*)d_in[1];
  const float* c0    = (const float*)d_in[2];
  const float* W_hi  = (const float*)d_in[3];
  const float* W_xi  = (const float*)d_in[4];
  const float* b_i   = (const float*)d_in[5];
  const float* W_hf  = (const float*)d_in[6];
  const float* W_xf  = (const float*)d_in[7];
  const float* b_f   = (const float*)d_in[8];
  const float* W_ho  = (const float*)d_in[9];
  const float* W_xo  = (const float*)d_in[10];
  const float* b_o   = (const float*)d_in[11];
  const float* W_hz  = (const float*)d_in[12];
  const float* W_xz  = (const float*)d_in[13];
  const float* b_z   = (const float*)d_in[14];
  const float* W_lin = (const float*)d_in[15];
  const float* b_lin = (const float*)d_in[16];
  const float* emb   = (const float*)d_in[17];

  float* out = (float*)d_out;
  char* ws = (char*)d_ws;
  // layout (bytes):
  char*   hb   = ws;                                              // 33*128*64*16 = 4,325,376
  char*   xb   = ws + 4325376;                                    // 32*128*64*16 = 4,194,304
  float*  psum = (float*)(ws + 8519680);                          // 32*313*64*4 = 2,564,096
  unsigned long long* pmax = (unsigned long long*)(ws + 11083776);// 32*313*64*8 = 5,128,192
  float*  inv  = (float*)(ws + 16211968);                         //        8,192
  int*    ctrs = (int*)(ws + 16220160);                           //    1,048,576

  k_init<<<128, 256, 0, stream>>>(h0, hb, ctrs);

  Params P;
  P.x = x; P.emb = emb; P.c0 = c0;
  P.Whi = W_hi; P.Whf = W_hf; P.Who = W_ho; P.Whz = W_hz;
  P.Wxi = W_xi; P.Wxf = W_xf; P.Wxo = W_xo; P.Wxz = W_xz;
  P.bi = b_i; P.bfg = b_f; P.bo = b_o; P.bz = b_z;
  P.W_lin = W_lin; P.b_lin = b_lin;
  P.out = out;
  P.hb = hb; P.xb = xb;
  P.psum = psum; P.pmax = pmax; P.inv = inv;
  P.ctr = ctrs;

  k_main<<<GRID, 256, 0, stream>>>(P);
}